// Round 13
// baseline (410.314 us; speedup 1.0000x reference)
//
#include <hip/hip_runtime.h>
#include <math.h>
#include <stdint.h>

// Problem constants
#define Bb   4
#define Tt   1024
#define Cc   1024
#define Hh   16
#define HKVn 8
#define Nn   64
#define MT   (Bb*Tt)
#define NC   32      // chunks per sequence
#define CL   32      // chunk length
#define NCAT 2432    // 1024+512+512+64+64+(32+32pad)+(160+32pad) -> 19*128

typedef __bf16 bf16x8_t __attribute__((ext_vector_type(8)));
typedef float  f32x4_t  __attribute__((ext_vector_type(4)));

__device__ __forceinline__ uint16_t f2bf(float f) {
    uint32_t u = __float_as_uint(f);
    uint32_t r = (u + 0x7fffu + ((u >> 16) & 1u)) >> 16;
    return (uint16_t)r;
}

// wave-broadcast: value held by lane l (VALU pipe, not LDS)
__device__ __forceinline__ float rlane(float v, int l) {
    return __uint_as_float(__builtin_amdgcn_readlane(__float_as_uint(v), l));
}

// async-stage one 64-float wave-uniform array into LDS (lane i -> l[i])
__device__ __forceinline__ void stage64(const float* g, float* l, int lane) {
    __builtin_amdgcn_global_load_lds(
        (const __attribute__((address_space(1))) uint32_t*)(g + lane),
        (__attribute__((address_space(3))) uint32_t*)l, 4, 0, 0);
}

// ---------------------------------------------------------------------------
// x -> bf16 convert + v_first passthrough copy (second tuple output), fused.
// ---------------------------------------------------------------------------
__global__ __launch_bounds__(256) void conv_copy_kernel(
    const float* __restrict__ x, uint16_t* __restrict__ xb,
    const float4* __restrict__ vfi, float4* __restrict__ out2, int n4)
{
    int i = blockIdx.x * blockDim.x + threadIdx.x;
    if (i >= n4) return;
    float4 v = reinterpret_cast<const float4*>(x)[i];
    ushort4 o;
    o.x = f2bf(v.x); o.y = f2bf(v.y); o.z = f2bf(v.z); o.w = f2bf(v.w);
    reinterpret_cast<ushort4*>(xb)[i] = o;
    out2[i] = vfi[i];
}

// ---------------------------------------------------------------------------
// All weight transposes in one launch. z selects the weight; Nsrc real cols
// zero-padded to Ndst, Ksrc real rows zero-padded to Kout.
// ---------------------------------------------------------------------------
__global__ __launch_bounds__(256) void transpose_all_kernel(
    const float* __restrict__ Wr, const float* __restrict__ Wk, const float* __restrict__ Wv,
    const float* __restrict__ w1, const float* __restrict__ a1, const float* __restrict__ v1,
    const float* __restrict__ g1, const float* __restrict__ Wo,
    const float* __restrict__ w2, const float* __restrict__ a2,
    const float* __restrict__ v2, const float* __restrict__ g2,
    uint16_t* __restrict__ WCAT, uint16_t* __restrict__ WoT,
    uint16_t* __restrict__ LW, uint16_t* __restrict__ LA,
    uint16_t* __restrict__ LV, uint16_t* __restrict__ LG)
{
    int z = blockIdx.z;
    const float* W; int Nsrc, Ndst, Ksrc, Kout, off; uint16_t* out;
    switch (z) {
        case 0:  W = Wr; Nsrc = 1024; Ndst = 1024; Ksrc = 1024; Kout = 1024; off = 0;    out = WCAT; break;
        case 1:  W = Wk; Nsrc = 512;  Ndst = 512;  Ksrc = 1024; Kout = 1024; off = 1024; out = WCAT; break;
        case 2:  W = Wv; Nsrc = 512;  Ndst = 512;  Ksrc = 1024; Kout = 1024; off = 1536; out = WCAT; break;
        case 3:  W = w1; Nsrc = 64;   Ndst = 64;   Ksrc = 1024; Kout = 1024; off = 2048; out = WCAT; break;
        case 4:  W = a1; Nsrc = 64;   Ndst = 64;   Ksrc = 1024; Kout = 1024; off = 2112; out = WCAT; break;
        case 5:  W = v1; Nsrc = 32;   Ndst = 64;   Ksrc = 1024; Kout = 1024; off = 2176; out = WCAT; break;
        case 6:  W = g1; Nsrc = 160;  Ndst = 192;  Ksrc = 1024; Kout = 1024; off = 2240; out = WCAT; break;
        case 7:  W = Wo; Nsrc = 1024; Ndst = 1024; Ksrc = 1024; Kout = 1024; off = 0;    out = WoT;  break;
        case 8:  W = w2; Nsrc = 1024; Ndst = 1024; Ksrc = 64;   Kout = 64;   off = 0;    out = LW;   break;
        case 9:  W = a2; Nsrc = 1024; Ndst = 1024; Ksrc = 64;   Kout = 64;   off = 0;    out = LA;   break;
        case 10: W = v2; Nsrc = 1024; Ndst = 1024; Ksrc = 32;   Kout = 64;   off = 0;    out = LV;   break;
        default: W = g2; Nsrc = 1024; Ndst = 1024; Ksrc = 160;  Kout = 192;  off = 0;    out = LG;   break;
    }
    int n0 = blockIdx.x * 32, k0 = blockIdx.y * 32;
    if (n0 >= Ndst || k0 >= Kout) return;
    __shared__ float tile[32][33];
    int tx = threadIdx.x & 31, ty = threadIdx.x >> 5; // 32 x 8
    #pragma unroll
    for (int i = 0; i < 32; i += 8) {
        int k = k0 + ty + i, n = n0 + tx;
        tile[ty + i][tx] = (k < Ksrc && n < Nsrc) ? W[(size_t)k * Nsrc + n] : 0.f;
    }
    __syncthreads();
    #pragma unroll
    for (int i = 0; i < 32; i += 8) {
        int n = n0 + ty + i, k = k0 + tx;
        if (n < Ndst) out[(size_t)(off + n) * Kout + k] = f2bf(tile[tx][ty + i]);
    }
}

// ---------------------------------------------------------------------------
// Fused stage-1 projection GEMM: C[M][2432] = XB[M][1024] @ WCAT^T.
// ---------------------------------------------------------------------------
__global__ __launch_bounds__(256) void gemm_bf16_proj(
    const uint16_t* __restrict__ A, const uint16_t* __restrict__ Bt,
    int M, int N, int K,
    float* __restrict__ R_, float* __restrict__ K_, float* __restrict__ V_,
    uint16_t* __restrict__ W1b, uint16_t* __restrict__ A1b,
    uint16_t* __restrict__ V1b, uint16_t* __restrict__ G1b)
{
    __shared__ __align__(16) uint16_t As[128 * 64];
    __shared__ __align__(16) uint16_t Bs[128 * 64];
    int tid  = threadIdx.x;
    int lane = tid & 63, wid = tid >> 6;
    int wm = (wid >> 1) * 64, wn = (wid & 1) * 64;
    int bm = blockIdx.y * 128, bn = blockIdx.x * 128;

    f32x4_t acc[4][4];
    #pragma unroll
    for (int i = 0; i < 4; ++i)
        #pragma unroll
        for (int j = 0; j < 4; ++j)
            #pragma unroll
            for (int e = 0; e < 4; ++e) acc[i][j][e] = 0.f;

    int rowS[4], kbS[4];
    #pragma unroll
    for (int i = 0; i < 4; ++i) {
        int d = (i * 256 + tid) * 16;
        int row = d >> 7;
        int kb = (d & 127) ^ ((row & 7) << 4);
        rowS[i] = row; kbS[i] = kb >> 1;
    }

    for (int k0 = 0; k0 < K; k0 += 64) {
        #pragma unroll
        for (int i = 0; i < 4; ++i) {
            const uint16_t* srcA = A + (size_t)(bm + rowS[i]) * K + k0 + kbS[i];
            uint16_t* ldsA = As + (i * 256 + wid * 64) * 8;
            __builtin_amdgcn_global_load_lds(
                (const __attribute__((address_space(1))) uint32_t*)srcA,
                (__attribute__((address_space(3))) uint32_t*)ldsA, 16, 0, 0);
            int nr = bn + rowS[i];
            const uint16_t* srcB = Bt + (size_t)(nr < N ? nr : 0) * K + k0 + kbS[i];
            uint16_t* ldsB = Bs + (i * 256 + wid * 64) * 8;
            __builtin_amdgcn_global_load_lds(
                (const __attribute__((address_space(1))) uint32_t*)srcB,
                (__attribute__((address_space(3))) uint32_t*)ldsB, 16, 0, 0);
        }
        __syncthreads();

        #pragma unroll
        for (int kk = 0; kk < 64; kk += 32) {
            int fb = (kk + ((lane >> 4) << 3)) << 1;
            bf16x8_t af[4], bfr[4];
            #pragma unroll
            for (int i = 0; i < 4; ++i) {
                int row = wm + i * 16 + (lane & 15);
                int byteA = (row << 7) + (fb ^ ((row & 7) << 4));
                af[i] = *reinterpret_cast<const bf16x8_t*>(
                    reinterpret_cast<const char*>(As) + byteA);
                int col = wn + i * 16 + (lane & 15);
                int byteB = (col << 7) + (fb ^ ((col & 7) << 4));
                bfr[i] = *reinterpret_cast<const bf16x8_t*>(
                    reinterpret_cast<const char*>(Bs) + byteB);
            }
            #pragma unroll
            for (int i = 0; i < 4; ++i)
                #pragma unroll
                for (int j = 0; j < 4; ++j)
                    acc[i][j] = __builtin_amdgcn_mfma_f32_16x16x32_bf16(
                        af[i], bfr[j], acc[i][j], 0, 0, 0);
        }
        __syncthreads();
    }

    #pragma unroll
    for (int i = 0; i < 4; ++i) {
        int row0 = bm + wm + i * 16 + ((lane >> 4) << 2);
        #pragma unroll
        for (int j = 0; j < 4; ++j) {
            int col = bn + wn + j * 16 + (lane & 15);
            if (col >= N) continue;
            #pragma unroll
            for (int rg = 0; rg < 4; ++rg) {
                float v = acc[i][j][rg];
                int row = row0 + rg;
                if (col < 1024)       R_[(size_t)row * 1024 + col] = v;
                else if (col < 1536)  K_[(size_t)row * 512 + (col - 1024)] = v;
                else if (col < 2048)  V_[(size_t)row * 512 + (col - 1536)] = v;
                else if (col < 2112)  W1b[(size_t)row * 64 + (col - 2048)] = f2bf(tanhf(v));
                else if (col < 2176)  A1b[(size_t)row * 64 + (col - 2112)] = f2bf(v);
                else if (col < 2240)  V1b[(size_t)row * 64 + (col - 2176)] = f2bf(v);
                else                  G1b[(size_t)row * 192 + (col - 2240)] = f2bf(1.f / (1.f + expf(-v)));
            }
        }
    }
}

// ---------------------------------------------------------------------------
// bf16 MFMA GEMM (plain epilogue) for the output projection.
// ---------------------------------------------------------------------------
__global__ __launch_bounds__(256) void gemm_bf16(
    const uint16_t* __restrict__ A, const uint16_t* __restrict__ Bt,
    float* __restrict__ C, int M, int N, int K)
{
    __shared__ __align__(16) uint16_t As[128 * 64];
    __shared__ __align__(16) uint16_t Bs[128 * 64];
    int tid  = threadIdx.x;
    int lane = tid & 63, wid = tid >> 6;
    int wm = (wid >> 1) * 64, wn = (wid & 1) * 64;
    int bm = blockIdx.y * 128, bn = blockIdx.x * 128;

    f32x4_t acc[4][4];
    #pragma unroll
    for (int i = 0; i < 4; ++i)
        #pragma unroll
        for (int j = 0; j < 4; ++j)
            #pragma unroll
            for (int e = 0; e < 4; ++e) acc[i][j][e] = 0.f;

    int rowS[4], kbS[4];
    #pragma unroll
    for (int i = 0; i < 4; ++i) {
        int d = (i * 256 + tid) * 16;
        int row = d >> 7;
        int kb = (d & 127) ^ ((row & 7) << 4);
        rowS[i] = row; kbS[i] = kb >> 1;
    }

    for (int k0 = 0; k0 < K; k0 += 64) {
        #pragma unroll
        for (int i = 0; i < 4; ++i) {
            const uint16_t* srcA = A + (size_t)(bm + rowS[i]) * K + k0 + kbS[i];
            uint16_t* ldsA = As + (i * 256 + wid * 64) * 8;
            __builtin_amdgcn_global_load_lds(
                (const __attribute__((address_space(1))) uint32_t*)srcA,
                (__attribute__((address_space(3))) uint32_t*)ldsA, 16, 0, 0);
            int nr = bn + rowS[i];
            const uint16_t* srcB = Bt + (size_t)(nr < N ? nr : 0) * K + k0 + kbS[i];
            uint16_t* ldsB = Bs + (i * 256 + wid * 64) * 8;
            __builtin_amdgcn_global_load_lds(
                (const __attribute__((address_space(1))) uint32_t*)srcB,
                (__attribute__((address_space(3))) uint32_t*)ldsB, 16, 0, 0);
        }
        __syncthreads();

        #pragma unroll
        for (int kk = 0; kk < 64; kk += 32) {
            int fb = (kk + ((lane >> 4) << 3)) << 1;
            bf16x8_t af[4], bfr[4];
            #pragma unroll
            for (int i = 0; i < 4; ++i) {
                int row = wm + i * 16 + (lane & 15);
                int byteA = (row << 7) + (fb ^ ((row & 7) << 4));
                af[i] = *reinterpret_cast<const bf16x8_t*>(
                    reinterpret_cast<const char*>(As) + byteA);
                int col = wn + i * 16 + (lane & 15);
                int byteB = (col << 7) + (fb ^ ((col & 7) << 4));
                bfr[i] = *reinterpret_cast<const bf16x8_t*>(
                    reinterpret_cast<const char*>(Bs) + byteB);
            }
            #pragma unroll
            for (int i = 0; i < 4; ++i)
                #pragma unroll
                for (int j = 0; j < 4; ++j)
                    acc[i][j] = __builtin_amdgcn_mfma_f32_16x16x32_bf16(
                        af[i], bfr[j], acc[i][j], 0, 0, 0);
        }
        __syncthreads();
    }

    #pragma unroll
    for (int i = 0; i < 4; ++i) {
        int row0 = bm + wm + i * 16 + ((lane >> 4) << 2);
        #pragma unroll
        for (int j = 0; j < 4; ++j) {
            int col = bn + wn + j * 16 + (lane & 15);
            if (col >= N) continue;
            #pragma unroll
            for (int rg = 0; rg < 4; ++rg)
                C[(size_t)(row0 + rg) * N + col] = acc[i][j][rg];
        }
    }
}

// ---------------------------------------------------------------------------
// Stage-2 LoRA GEMMs as one fused MFMA kernel. 4 segments, INTERLEAVED.
// ---------------------------------------------------------------------------
__global__ __launch_bounds__(256) void lora2_mfma(
    const uint16_t* __restrict__ W1b, const uint16_t* __restrict__ A1b,
    const uint16_t* __restrict__ V1b, const uint16_t* __restrict__ G1b,
    const uint16_t* __restrict__ LW, const uint16_t* __restrict__ LA,
    const uint16_t* __restrict__ LV, const uint16_t* __restrict__ LG,
    const float* __restrict__ w0, const float* __restrict__ a0, const float* __restrict__ v0,
    const float* __restrict__ VRAW, const float* __restrict__ vfi,
    const float* __restrict__ ABUF,
    float* __restrict__ DEC, float* __restrict__ AARR,
    float* __restrict__ VFIN, float* __restrict__ GARR)
{
    int seg = blockIdx.x & 3;
    int bn = (blockIdx.x >> 2) * 128;
    int bm = blockIdx.y * 128;

    const uint16_t* A; const uint16_t* Bt; int K;
    if (seg == 0)      { A = W1b; Bt = LW; K = 64; }
    else if (seg == 1) { A = A1b; Bt = LA; K = 64; }
    else if (seg == 2) { A = V1b; Bt = LV; K = 64; }
    else               { A = G1b; Bt = LG; K = 192; }

    __shared__ __align__(16) uint16_t As[128 * 64];
    __shared__ __align__(16) uint16_t Bs[128 * 64];
    int tid  = threadIdx.x;
    int lane = tid & 63, wid = tid >> 6;
    int wm = (wid >> 1) * 64, wn = (wid & 1) * 64;

    f32x4_t acc[4][4];
    #pragma unroll
    for (int i = 0; i < 4; ++i)
        #pragma unroll
        for (int j = 0; j < 4; ++j)
            #pragma unroll
            for (int e = 0; e < 4; ++e) acc[i][j][e] = 0.f;

    int rowS[4], kbS[4];
    #pragma unroll
    for (int i = 0; i < 4; ++i) {
        int d = (i * 256 + tid) * 16;
        int row = d >> 7;
        int kb = (d & 127) ^ ((row & 7) << 4);
        rowS[i] = row; kbS[i] = kb >> 1;
    }

    for (int k0 = 0; k0 < K; k0 += 64) {
        #pragma unroll
        for (int i = 0; i < 4; ++i) {
            const uint16_t* srcA = A + (size_t)(bm + rowS[i]) * K + k0 + kbS[i];
            uint16_t* ldsA = As + (i * 256 + wid * 64) * 8;
            __builtin_amdgcn_global_load_lds(
                (const __attribute__((address_space(1))) uint32_t*)srcA,
                (__attribute__((address_space(3))) uint32_t*)ldsA, 16, 0, 0);
            const uint16_t* srcB = Bt + (size_t)(bn + rowS[i]) * K + k0 + kbS[i];
            uint16_t* ldsB = Bs + (i * 256 + wid * 64) * 8;
            __builtin_amdgcn_global_load_lds(
                (const __attribute__((address_space(1))) uint32_t*)srcB,
                (__attribute__((address_space(3))) uint32_t*)ldsB, 16, 0, 0);
        }
        __syncthreads();

        #pragma unroll
        for (int kk = 0; kk < 64; kk += 32) {
            int fb = (kk + ((lane >> 4) << 3)) << 1;
            bf16x8_t af[4], bfr[4];
            #pragma unroll
            for (int i = 0; i < 4; ++i) {
                int row = wm + i * 16 + (lane & 15);
                int byteA = (row << 7) + (fb ^ ((row & 7) << 4));
                af[i] = *reinterpret_cast<const bf16x8_t*>(
                    reinterpret_cast<const char*>(As) + byteA);
                int col = wn + i * 16 + (lane & 15);
                int byteB = (col << 7) + (fb ^ ((col & 7) << 4));
                bfr[i] = *reinterpret_cast<const bf16x8_t*>(
                    reinterpret_cast<const char*>(Bs) + byteB);
            }
            #pragma unroll
            for (int i = 0; i < 4; ++i)
                #pragma unroll
                for (int j = 0; j < 4; ++j)
                    acc[i][j] = __builtin_amdgcn_mfma_f32_16x16x32_bf16(
                        af[i], bfr[j], acc[i][j], 0, 0, 0);
        }
        __syncthreads();
    }

    #pragma unroll
    for (int i = 0; i < 4; ++i) {
        int row0 = bm + wm + i * 16 + ((lane >> 4) << 2);
        #pragma unroll
        for (int j = 0; j < 4; ++j) {
            int col = bn + wn + j * 16 + (lane & 15);
            #pragma unroll
            for (int rg = 0; rg < 4; ++rg) {
                float v = acc[i][j][rg];
                int row = row0 + rg;
                if (seg == 0) {
                    // exp(-exp(-softplus(-z)-0.5)) == exp(-e^{-0.5}*sigmoid(z))
                    float z = v + w0[col];
                    float sig = 1.f / (1.f + expf(-z));
                    DEC[(size_t)row * 1024 + col] = expf(-0.6065306597f * sig);
                } else if (seg == 1) {
                    float kk = -ABUF[(size_t)row * 512 + ((col >> 7) << 6) + (col & 63)];
                    AARR[(size_t)row * 1024 + col] = kk / (1.f + expf(-(v + a0[col])));
                } else if (seg == 2) {
                    float m = 1.f / (1.f + expf(-(v + v0[col])));
                    float vr = VRAW[(size_t)row * 512 + ((col >> 7) << 6) + (col & 63)];
                    float vf = vfi[(size_t)row * 1024 + col];
                    VFIN[(size_t)row * 1024 + col] = vr + (vf - vr) * m;
                } else {
                    GARR[(size_t)row * 1024 + col] = v;
                }
            }
        }
    }
}

// ---------------------------------------------------------------------------
// Fused RMS-norm + RoPE (R & K) + prep (kk -> ABUF, BON). cos/sin inline.
// ---------------------------------------------------------------------------
__global__ __launch_bounds__(64) void normrope_prep(
    float* __restrict__ RRAW, float* __restrict__ KRAW,
    float* __restrict__ ABUF,
    const float* __restrict__ rnw, const float* __restrict__ knw,
    const float* __restrict__ rk,
    float* __restrict__ BON)
{
    int blk = blockIdx.x;      // bt*8 + hk
    int hk = blk & 7;
    int bt = blk >> 3;
    int b = bt >> 10, t = bt & 1023;
    int lane = threadIdx.x;
    int fi = lane & 31;
    float invf = powf(1.0e6f, -(float)fi * (1.0f / 32.0f));
    float fr = (float)t * invf;
    float c = cosf(fr), s = sinf(fr);

    // ---- K head: norm + rope + kk ----
    size_t kidx = ((size_t)bt * 8 + hk) * 64 + lane;
    float k = KRAW[kidx];
    float ss = k * k;
    #pragma unroll
    for (int m = 1; m < 64; m <<= 1) ss += __shfl_xor(ss, m, 64);
    float kn = k * rsqrtf(ss * (1.f / 64.f) + 1e-6f) * knw[lane];
    float kp = __shfl_xor(kn, 32, 64);
    float kroped = fmaf(kn, c, ((lane < 32) ? -kp : kp) * s);
    KRAW[kidx] = kroped;

    float ss2 = kroped * kroped;
    #pragma unroll
    for (int m = 1; m < 64; m <<= 1) ss2 += __shfl_xor(ss2, m, 64);
    float kk = kroped / fmaxf(sqrtf(ss2), 1e-12f);
    ABUF[kidx] = -kk;

    // ---- R heads (2 per kv head): norm + rope + BON ----
    #pragma unroll
    for (int rep = 0; rep < 2; ++rep) {
        int h = hk * 2 + rep;
        size_t cidx = (size_t)bt * 1024 + h * 64 + lane;
        float r = RRAW[cidx];
        float ssr = r * r;
        #pragma unroll
        for (int m = 1; m < 64; m <<= 1) ssr += __shfl_xor(ssr, m, 64);
        float rn = r * rsqrtf(ssr * (1.f / 64.f) + 1e-6f) * rnw[lane];
        float rp = __shfl_xor(rn, 32, 64);
        float rroped = fmaf(rn, c, ((lane < 32) ? -rp : rp) * s);
        RRAW[cidx] = rroped;

        float bon = rroped * kroped * rk[h * 64 + lane];
        #pragma unroll
        for (int m = 1; m < 64; m <<= 1) bon += __shfl_xor(bon, m, 64);
        if (lane == 0) BON[((size_t)(b * 16 + h)) * 1024 + t] = bon;
    }
}

// ---------------------------------------------------------------------------
// wkv_pass1 v7: r10 structure, but the phase-A `a` array moves from LDS to
// per-lane registers + v_readlane (phase A is a pure reduction — no per-j
// dep chain, unlike r8's failed full-readlane phase B). LDS reads/step:
// 81 -> 65. Staging: 5 global_load_lds + 1 vector load, vmcnt(6).
// NO occupancy clamp.
// ---------------------------------------------------------------------------
__global__ __launch_bounds__(64) void wkv_pass1(
    const float* __restrict__ R, const float* __restrict__ Kv,
    const float* __restrict__ Ab, const float* __restrict__ Bhat,
    const float* __restrict__ Dd, const float* __restrict__ Vv,
    float* __restrict__ Q, float* __restrict__ Y0,
    float* __restrict__ PLT, float* __restrict__ ZL)
{
    int blk = blockIdx.x;           // bh*NC + c
    int c   = blk & (NC - 1);
    int bh  = blk >> 5;
    int h   = bh & 15;
    int b   = bh >> 4;
    int hk  = h >> 1;
    int lane = threadIdx.x;
    int t0 = c * CL;

    size_t cb = ((size_t)(b * 1024 + t0)) * 1024 + h * 64;
    size_t kb = ((size_t)(b * 1024 + t0)) * 512 + hk * 64;
    size_t qb = (((size_t)bh) * 1024 + t0) * 64;

    __shared__ __align__(16) float sB[2][64], sD[2][64],
                                   sR[2][64], sK[2][64], sV[2][64];

    float SP[64], SZ[64];
    #pragma unroll
    for (int j = 0; j < 64; ++j) { SP[j] = (j == lane) ? 1.f : 0.f; SZ[j] = 0.f; }

    auto stage = [&](int u, int buf) {
        stage64(Bhat + cb + (size_t)u * 1024, &sB[buf][0], lane);
        stage64(Dd   + cb + (size_t)u * 1024, &sD[buf][0], lane);
        stage64(R    + cb + (size_t)u * 1024, &sR[buf][0], lane);
        stage64(Kv   + kb + (size_t)u * 512,  &sK[buf][0], lane);
        stage64(Vv   + cb + (size_t)u * 1024, &sV[buf][0], lane);
    };
    stage(0, 0);
    float av = Ab[kb + lane];

    for (int u = 0; u < CL; ++u) {
        int un = (u + 1 < CL) ? u + 1 : u;
        stage(un, (u + 1) & 1);
        float an = Ab[kb + (size_t)un * 512 + lane];
        asm volatile("s_waitcnt vmcnt(6)" ::: "memory");
        int cur = u & 1;
        float v = sV[cur][lane];

        // phase A: pa = SP.a, za = SZ.a — a[j] broadcast via readlane (VALU)
        float pa0 = 0.f, pa1 = 0.f, za0 = 0.f, za1 = 0.f;
        #pragma unroll
        for (int j = 0; j < 64; j += 2) {
            float aj0 = rlane(av, j), aj1 = rlane(av, j + 1);
            pa0 = fmaf(SP[j],     aj0, pa0); za0 = fmaf(SZ[j],     aj0, za0);
            pa1 = fmaf(SP[j + 1], aj1, pa1); za1 = fmaf(SZ[j + 1], aj1, za1);
        }
        float pa = pa0 + pa1;
        float za = za0 + za1;

        // phase B: update both states (LDS b128 operands); q = SP.r, y0 = SZ.r
        float q0 = 0.f, q1 = 0.f, y0a = 0.f, y1a = 0.f;
        #pragma unroll
        for (int jc = 0; jc < 16; ++jc) {
            float4 d4 = *reinterpret_cast<const float4*>(&sD[cur][jc * 4]);
            float4 b4 = *reinterpret_cast<const float4*>(&sB[cur][jc * 4]);
            float4 k4 = *reinterpret_cast<const float4*>(&sK[cur][jc * 4]);
            float4 r4 = *reinterpret_cast<const float4*>(&sR[cur][jc * 4]);
            SP[jc*4+0] = fmaf(SP[jc*4+0], d4.x, pa * b4.x); q0  = fmaf(SP[jc*4+0], r4.x, q0);
            SZ[jc*4+0] = fmaf(SZ[jc*4+0], d4.x, fmaf(za, b4.x, v * k4.x)); y0a = fmaf(SZ[jc*4+0], r4.x, y0a);
            SP[jc*4+1] = fmaf(SP[jc*4+1], d4.y, pa * b4.y); q1  = fmaf(SP[jc*4+1], r4.y, q1);
            SZ[jc*4+1] = fmaf(SZ[jc*4+1], d4.y, fmaf(za, b4.y, v * k4.y)); y1a = fmaf(SZ[jc*4+1], r4.y, y1a);
            SP[jc*4+2] = fmaf(SP[jc*4+2], d4.z, pa * b4.z); q0  = fmaf(SP[jc*4+2], r4.z, q0);
            SZ[jc*4+2] = fmaf(SZ[jc*4+2], d4.z, fmaf(za, b4.z, v * k4.z)); y0a = fmaf(SZ[jc*4+2], r4.z, y0a);
            SP[jc*4+3] = fmaf(SP[jc*4+3], d4.w, pa * b4.w); q1  = fmaf(SP[jc*4+3], r4.w, q1);
            SZ[jc*4+3] = fmaf(SZ[jc*4+3], d4.w, fmaf(za, b4.w, v * k4.w)); y1a = fmaf(SZ[jc*4+3], r4.w, y1a);
        }
        Q[qb + (size_t)u * 64 + lane]    = q0 + q1;
        Y0[cb + (size_t)u * 1024 + lane] = y0a + y1a;
        av = an;
    }

    // P transposed + swizzled: PLT[col*64 + (row ^ ((col&7)<<2))] = P[row][col]
    size_t pbT = (size_t)blk * 4096;
    #pragma unroll
    for (int j = 0; j < 64; ++j)
        PLT[pbT + j * 64 + (lane ^ ((j & 7) << 2))] = SP[j];
    size_t pb = pbT + (size_t)lane * 64;
    #pragma unroll
    for (int j = 0; j < 64; j += 4)
        *reinterpret_cast<float4*>(&ZL[pb + j]) =
            make_float4(SZ[j], SZ[j + 1], SZ[j + 2], SZ[j + 3]);
}

// ---------------------------------------------------------------------------
// wkv_pass2 (r8 version): chunk-state propagation, row-parallel. 256 blocks =
// (bh, 16-row group); 4 waves x 4 rows, lane = column. S rows in VGPRs;
// row-broadcast via readlane; P staged column-major+swizzled to LDS.
// ---------------------------------------------------------------------------
__global__ __launch_bounds__(256) void wkv_pass2(
    const float* __restrict__ PLT, float* ZLio)
{
    int blk = blockIdx.x;        // bh*4 + rg
    int rg  = blk & 3;
    int bh  = blk >> 2;
    int tid = threadIdx.x, lane = tid & 63, wv = tid >> 6;

    __shared__ __align__(16) float Pld[2][4096];
    __shared__ __align__(16) float Zld[2][1024];

    float S0 = 0.f, S1 = 0.f, S2 = 0.f, S3 = 0.f;

    auto stage = [&](int cc, int buf) {
        size_t pbase = ((size_t)bh * NC + cc) * 4096;
        #pragma unroll
        for (int i = 0; i < 4; ++i) {
            const float* src = PLT + pbase + (size_t)(i * 256 + tid) * 4;
            float* dst = &Pld[buf][(i * 256 + wv * 64) * 4];
            __builtin_amdgcn_global_load_lds(
                (const __attribute__((address_space(1))) uint32_t*)src,
                (__attribute__((address_space(3))) uint32_t*)dst, 16, 0, 0);
        }
        const float* zsrc = ZLio + pbase + (size_t)rg * 1024 + (size_t)tid * 4;
        float* zdst = &Zld[buf][wv * 256];
        __builtin_amdgcn_global_load_lds(
            (const __attribute__((address_space(1))) uint32_t*)zsrc,
            (__attribute__((address_space(3))) uint32_t*)zdst, 16, 0, 0);
    };

    stage(0, 0);

    for (int cc = 0; cc < NC; ++cc) {
        int cur = cc & 1;
        if (cc + 1 < NC) {
            stage(cc + 1, cur ^ 1);
            asm volatile("s_waitcnt vmcnt(5)" ::: "memory");
        } else {
            asm volatile("s_waitcnt vmcnt(0)" ::: "memory");
        }
        __syncthreads();

        size_t sb = ((size_t)bh * NC + cc) * 4096 + (size_t)(rg * 16 + wv * 4) * 64 + lane;
        ZLio[sb]       = S0;
        ZLio[sb + 64]  = S1;
        ZLio[sb + 128] = S2;
        ZLio[sb + 192] = S3;
        if (cc == NC - 1) break;

        int zb = (wv * 4) * 64 + lane;
        float acc0 = Zld[cur][zb],       acc1 = Zld[cur][zb + 64],
              acc2 = Zld[cur][zb + 128], acc3 = Zld[cur][zb + 192];
        const float* pcol = &Pld[cur][lane * 64];
        int swz = (lane & 7) << 2;
        #pragma unroll
        for (int m4 = 0; m4 < 64; m4 += 4) {
            float4 p4 = *reinterpret_cast<const float4*>(&pcol[m4 ^ swz]);
            #pragma unroll
            for (int s = 0; s < 4; ++s) {
                float pv = (&p4.x)[s];
                acc0 = fmaf(rlane(S0, m4 + s), pv, acc0);
                acc1 = fmaf(rlane(S1, m4 + s), pv, acc1);
                acc2 = fmaf(rlane(S2, m4 + s), pv, acc2);
                acc3 = fmaf(rlane(S3, m4 + s), pv, acc3);
            }
        }
        S0 = acc0; S1 = acc1; S2 = acc2; S3 = acc3;
        __syncthreads();
    }
}

// ---------------------------------------------------------------------------
// wkv_pass3: y = (y0 + Sstart.q + bon*v) * g -> bf16 for the Wo GEMM.
// ---------------------------------------------------------------------------
__global__ __launch_bounds__(64) void wkv_pass3(
    const float* __restrict__ SST, const float* __restrict__ Q,
    const float* __restrict__ Vv, const float* __restrict__ G,
    const float* __restrict__ BON, const float* __restrict__ Y0,
    uint16_t* __restrict__ Yb)
{
    int blk = blockIdx.x;   // bh*NC + c
    int c = blk & (NC - 1), bh = blk >> 5, h = bh & 15, b = bh >> 4;
    int lane = threadIdx.x;
    int t0 = c * CL;

    __shared__ __align__(16) float qs[2][64];
    __shared__ float bons[CL];
    if (lane < CL) bons[lane] = BON[((size_t)bh) * 1024 + t0 + lane];

    float S[64];
    size_t sb = ((size_t)blk) * 4096 + (size_t)lane * 64;
    #pragma unroll
    for (int jc = 0; jc < 16; ++jc) {
        float4 s4 = *reinterpret_cast<const float4*>(&SST[sb + jc * 4]);
        S[jc*4+0] = s4.x; S[jc*4+1] = s4.y; S[jc*4+2] = s4.z; S[jc*4+3] = s4.w;
    }

    size_t cb = ((size_t)(b * 1024 + t0)) * 1024 + h * 64 + lane;
    size_t qbase = (((size_t)bh) * 1024 + t0) * 64;

    stage64(Q + qbase, &qs[0][0], lane);
    for (int u = 0; u < CL; ++u) {
        int un = (u + 1 < CL) ? u + 1 : u;
        stage64(Q + qbase + (size_t)un * 64, &qs[(u + 1) & 1][0], lane);
        asm volatile("s_waitcnt vmcnt(1)" ::: "memory");
        int cur = u & 1;

        float d0 = 0.f, d1 = 0.f, d2 = 0.f, d3 = 0.f;
        #pragma unroll
        for (int jc = 0; jc < 16; ++jc) {
            float4 q4 = *reinterpret_cast<const float4*>(&qs[cur][jc * 4]);
            d0 = fmaf(S[jc*4+0], q4.x, d0);
            d1 = fmaf(S[jc*4+1], q4.y, d1);
            d2 = fmaf(S[jc*4+2], q4.z, d2);
            d3 = fmaf(S[jc*4+3], q4.w, d3);
        }
        float dot = (d0 + d1) + (d2 + d3);
        float y0 = Y0[cb + (size_t)u * 1024];
        float vc = Vv[cb + (size_t)u * 1024];
        float gc = G[cb + (size_t)u * 1024];
        float bon = bons[u];
        Yb[cb + (size_t)u * 1024] = f2bf((y0 + dot + bon * vc) * gc);
    }
}

// ---------------------------------------------------------------------------
extern "C" void kernel_launch(void* const* d_in, const int* in_sizes, int n_in,
                              void* d_out, int out_size, void* d_ws, size_t ws_size,
                              hipStream_t stream)
{
    const float* x   = (const float*)d_in[0];
    const float* vfi = (const float*)d_in[1];
    const float* Wr  = (const float*)d_in[2];
    const float* Wk  = (const float*)d_in[3];
    const float* Wv  = (const float*)d_in[4];
    const float* Wo  = (const float*)d_in[5];
    const float* w0  = (const float*)d_in[6];
    const float* w1  = (const float*)d_in[7];
    const float* w2  = (const float*)d_in[8];
    const float* a0  = (const float*)d_in[9];
    const float* a1  = (const float*)d_in[10];
    const float* a2  = (const float*)d_in[11];
    const float* v0  = (const float*)d_in[12];
    const float* v1  = (const float*)d_in[13];
    const float* v2  = (const float*)d_in[14];
    const float* g1  = (const float*)d_in[15];
    const float* g2  = (const float*)d_in[16];
    const float* rk  = (const float*)d_in[17];
    const float* rnw = (const float*)d_in[18];
    const float* knw = (const float*)d_in[19];

    float* ws = (float*)d_ws;
    size_t o = 0;
    float* RRAW = ws + o; o += (size_t)MT * 1024;
    float* KRAW = ws + o; o += (size_t)MT * 512;
    float* VRAW = ws + o; o += (size_t)MT * 512;
    float* DEC  = ws + o; o += (size_t)MT * 1024;
    float* AARR = ws + o; o += (size_t)MT * 1024;
    float* GARR = ws + o; o += (size_t)MT * 1024;
    float* VFIN = ws + o; o += (size_t)MT * 1024;
    float* YARR = ws + o; o += (size_t)MT * 1024;  // y0 from pass1
    float* ABUF = ws + o; o += (size_t)MT * 512;
    float* QBUF = ws + o; o += (size_t)MT * 1024;
    float* PLB  = ws + o; o += (size_t)(Bb * Hh * NC) * 4096;  // 32 MB (transposed+swizzled)
    float* ZLB  = ws + o; o += (size_t)(Bb * Hh * NC) * 4096;  // 32 MB (becomes SST)
    float* BON  = ws + o; o += (size_t)64 * 1024;
    uint16_t* XB   = (uint16_t*)(ws + o); o += (size_t)MT * 512;
    uint16_t* WCAT = (uint16_t*)(ws + o); o += (size_t)NCAT * 512;
    uint16_t* WoT  = (uint16_t*)(ws + o); o += (size_t)1024 * 512;
    uint16_t* W1b  = (uint16_t*)(ws + o); o += (size_t)MT * 32;   // [MT][64] bf16
    uint16_t* A1b  = (uint16_t*)(ws + o); o += (size_t)MT * 32;
    uint16_t* V1b  = (uint16_t*)(ws + o); o += (size_t)MT * 32;   // [MT][64], cols 32+ zero
    uint16_t* G1b  = (uint16_t*)(ws + o); o += (size_t)MT * 96;   // [MT][192], cols 160+ zero
    uint16_t* LW   = (uint16_t*)(ws + o); o += (size_t)1024 * 32; // w2^T [1024][64]
    uint16_t* LA   = (uint16_t*)(ws + o); o += (size_t)1024 * 32;
    uint16_t* LV   = (uint16_t*)(ws + o); o += (size_t)1024 * 32;
    uint16_t* LG   = (uint16_t*)(ws + o); o += (size_t)1024 * 96; // g2^T [1024][192]
    uint16_t* YB = XB;          // alias: XB dead after stage-1 GEMM

    conv_copy_kernel<<<dim3(MT * 1024 / 4 / 256), dim3(256), 0, stream>>>(
        x, XB, (const float4*)vfi, (float4*)((float*)d_out + (size_t)MT * 1024), MT * 1024 / 4);
    transpose_all_kernel<<<dim3(32, 32, 12), dim3(256), 0, stream>>>(
        Wr, Wk, Wv, w1, a1, v1, g1, Wo, w2, a2, v2, g2, WCAT, WoT, LW, LA, LV, LG);

    dim3 blk(256);

    // stage 1: all projections in one bf16 MFMA GEMM (N = 2432)
    gemm_bf16_proj<<<dim3(NCAT / 128, MT / 128), blk, 0, stream>>>(
        XB, WCAT, MT, NCAT, 1024, RRAW, KRAW, VRAW, W1b, A1b, V1b, G1b);

    // stage 2: fused RMS norm + RoPE + kk/BON prep (before lora2: it feeds ABUF)
    normrope_prep<<<dim3(MT * HKVn), dim3(64), 0, stream>>>(
        RRAW, KRAW, ABUF, rnw, knw, rk, BON);

    // stage 3: all LoRA second matmuls in one fused MFMA launch (interleaved segs)
    lora2_mfma<<<dim3(32, MT / 128), blk, 0, stream>>>(
        W1b, A1b, V1b, G1b, LW, LA, LV, LG, w0, a0, v0, VRAW, vfi, ABUF,
        DEC, AARR, VFIN, GARR);

    // stage 4: chunk-parallel WKV scan
    wkv_pass1<<<dim3(Bb * Hh * NC), dim3(64), 0, stream>>>(
        RRAW, KRAW, ABUF, AARR, DEC, VFIN, QBUF, YARR, PLB, ZLB);
    wkv_pass2<<<dim3(Bb * Hh * 4), dim3(256), 0, stream>>>(PLB, ZLB);
    wkv_pass3<<<dim3(Bb * Hh * NC), dim3(64), 0, stream>>>(
        ZLB, QBUF, VFIN, GARR, BON, YARR, YB);

    // stage 5: out = (y*g) @ Wo (bf16 MFMA)
    gemm_bf16<<<dim3(1024 / 128, MT / 128), blk, 0, stream>>>(
        YB, WoT, (float*)d_out, MT, 1024, 1024);
}

// Round 14
// 404.813 us; speedup vs baseline: 1.0136x; 1.0136x over previous
//
#include <hip/hip_runtime.h>
#include <math.h>
#include <stdint.h>

// Problem constants
#define Bb   4
#define Tt   1024
#define Cc   1024
#define Hh   16
#define HKVn 8
#define Nn   64
#define MT   (Bb*Tt)
#define NC   32      // chunks per sequence
#define CL   32      // chunk length
#define NCAT 2432    // 1024+512+512+64+64+(32+32pad)+(160+32pad) -> 19*128

typedef __bf16 bf16x8_t __attribute__((ext_vector_type(8)));
typedef float  f32x4_t  __attribute__((ext_vector_type(4)));

__device__ __forceinline__ uint16_t f2bf(float f) {
    uint32_t u = __float_as_uint(f);
    uint32_t r = (u + 0x7fffu + ((u >> 16) & 1u)) >> 16;
    return (uint16_t)r;
}

// wave-broadcast: value held by lane l (VALU pipe, not LDS)
__device__ __forceinline__ float rlane(float v, int l) {
    return __uint_as_float(__builtin_amdgcn_readlane(__float_as_uint(v), l));
}

// async-stage one 64-float wave-uniform array into LDS (lane i -> l[i])
__device__ __forceinline__ void stage64(const float* g, float* l, int lane) {
    __builtin_amdgcn_global_load_lds(
        (const __attribute__((address_space(1))) uint32_t*)(g + lane),
        (__attribute__((address_space(3))) uint32_t*)l, 4, 0, 0);
}

// ---------------------------------------------------------------------------
// x -> bf16 convert + v_first passthrough copy (second tuple output), fused.
// ---------------------------------------------------------------------------
__global__ __launch_bounds__(256) void conv_copy_kernel(
    const float* __restrict__ x, uint16_t* __restrict__ xb,
    const float4* __restrict__ vfi, float4* __restrict__ out2, int n4)
{
    int i = blockIdx.x * blockDim.x + threadIdx.x;
    if (i >= n4) return;
    float4 v = reinterpret_cast<const float4*>(x)[i];
    ushort4 o;
    o.x = f2bf(v.x); o.y = f2bf(v.y); o.z = f2bf(v.z); o.w = f2bf(v.w);
    reinterpret_cast<ushort4*>(xb)[i] = o;
    out2[i] = vfi[i];
}

// ---------------------------------------------------------------------------
// All weight transposes in one launch. z selects the weight; Nsrc real cols
// zero-padded to Ndst, Ksrc real rows zero-padded to Kout.
// ---------------------------------------------------------------------------
__global__ __launch_bounds__(256) void transpose_all_kernel(
    const float* __restrict__ Wr, const float* __restrict__ Wk, const float* __restrict__ Wv,
    const float* __restrict__ w1, const float* __restrict__ a1, const float* __restrict__ v1,
    const float* __restrict__ g1, const float* __restrict__ Wo,
    const float* __restrict__ w2, const float* __restrict__ a2,
    const float* __restrict__ v2, const float* __restrict__ g2,
    uint16_t* __restrict__ WCAT, uint16_t* __restrict__ WoT,
    uint16_t* __restrict__ LW, uint16_t* __restrict__ LA,
    uint16_t* __restrict__ LV, uint16_t* __restrict__ LG)
{
    int z = blockIdx.z;
    const float* W; int Nsrc, Ndst, Ksrc, Kout, off; uint16_t* out;
    switch (z) {
        case 0:  W = Wr; Nsrc = 1024; Ndst = 1024; Ksrc = 1024; Kout = 1024; off = 0;    out = WCAT; break;
        case 1:  W = Wk; Nsrc = 512;  Ndst = 512;  Ksrc = 1024; Kout = 1024; off = 1024; out = WCAT; break;
        case 2:  W = Wv; Nsrc = 512;  Ndst = 512;  Ksrc = 1024; Kout = 1024; off = 1536; out = WCAT; break;
        case 3:  W = w1; Nsrc = 64;   Ndst = 64;   Ksrc = 1024; Kout = 1024; off = 2048; out = WCAT; break;
        case 4:  W = a1; Nsrc = 64;   Ndst = 64;   Ksrc = 1024; Kout = 1024; off = 2112; out = WCAT; break;
        case 5:  W = v1; Nsrc = 32;   Ndst = 64;   Ksrc = 1024; Kout = 1024; off = 2176; out = WCAT; break;
        case 6:  W = g1; Nsrc = 160;  Ndst = 192;  Ksrc = 1024; Kout = 1024; off = 2240; out = WCAT; break;
        case 7:  W = Wo; Nsrc = 1024; Ndst = 1024; Ksrc = 1024; Kout = 1024; off = 0;    out = WoT;  break;
        case 8:  W = w2; Nsrc = 1024; Ndst = 1024; Ksrc = 64;   Kout = 64;   off = 0;    out = LW;   break;
        case 9:  W = a2; Nsrc = 1024; Ndst = 1024; Ksrc = 64;   Kout = 64;   off = 0;    out = LA;   break;
        case 10: W = v2; Nsrc = 1024; Ndst = 1024; Ksrc = 32;   Kout = 64;   off = 0;    out = LV;   break;
        default: W = g2; Nsrc = 1024; Ndst = 1024; Ksrc = 160;  Kout = 192;  off = 0;    out = LG;   break;
    }
    int n0 = blockIdx.x * 32, k0 = blockIdx.y * 32;
    if (n0 >= Ndst || k0 >= Kout) return;
    __shared__ float tile[32][33];
    int tx = threadIdx.x & 31, ty = threadIdx.x >> 5; // 32 x 8
    #pragma unroll
    for (int i = 0; i < 32; i += 8) {
        int k = k0 + ty + i, n = n0 + tx;
        tile[ty + i][tx] = (k < Ksrc && n < Nsrc) ? W[(size_t)k * Nsrc + n] : 0.f;
    }
    __syncthreads();
    #pragma unroll
    for (int i = 0; i < 32; i += 8) {
        int n = n0 + ty + i, k = k0 + tx;
        if (n < Ndst) out[(size_t)(off + n) * Kout + k] = f2bf(tile[tx][ty + i]);
    }
}

// ---------------------------------------------------------------------------
// Fused stage-1 projection GEMM: C[M][2432] = XB[M][1024] @ WCAT^T.
// ---------------------------------------------------------------------------
__global__ __launch_bounds__(256) void gemm_bf16_proj(
    const uint16_t* __restrict__ A, const uint16_t* __restrict__ Bt,
    int M, int N, int K,
    float* __restrict__ R_, float* __restrict__ K_, float* __restrict__ V_,
    uint16_t* __restrict__ W1b, uint16_t* __restrict__ A1b,
    uint16_t* __restrict__ V1b, uint16_t* __restrict__ G1b)
{
    __shared__ __align__(16) uint16_t As[128 * 64];
    __shared__ __align__(16) uint16_t Bs[128 * 64];
    int tid  = threadIdx.x;
    int lane = tid & 63, wid = tid >> 6;
    int wm = (wid >> 1) * 64, wn = (wid & 1) * 64;
    int bm = blockIdx.y * 128, bn = blockIdx.x * 128;

    f32x4_t acc[4][4];
    #pragma unroll
    for (int i = 0; i < 4; ++i)
        #pragma unroll
        for (int j = 0; j < 4; ++j)
            #pragma unroll
            for (int e = 0; e < 4; ++e) acc[i][j][e] = 0.f;

    int rowS[4], kbS[4];
    #pragma unroll
    for (int i = 0; i < 4; ++i) {
        int d = (i * 256 + tid) * 16;
        int row = d >> 7;
        int kb = (d & 127) ^ ((row & 7) << 4);
        rowS[i] = row; kbS[i] = kb >> 1;
    }

    for (int k0 = 0; k0 < K; k0 += 64) {
        #pragma unroll
        for (int i = 0; i < 4; ++i) {
            const uint16_t* srcA = A + (size_t)(bm + rowS[i]) * K + k0 + kbS[i];
            uint16_t* ldsA = As + (i * 256 + wid * 64) * 8;
            __builtin_amdgcn_global_load_lds(
                (const __attribute__((address_space(1))) uint32_t*)srcA,
                (__attribute__((address_space(3))) uint32_t*)ldsA, 16, 0, 0);
            int nr = bn + rowS[i];
            const uint16_t* srcB = Bt + (size_t)(nr < N ? nr : 0) * K + k0 + kbS[i];
            uint16_t* ldsB = Bs + (i * 256 + wid * 64) * 8;
            __builtin_amdgcn_global_load_lds(
                (const __attribute__((address_space(1))) uint32_t*)srcB,
                (__attribute__((address_space(3))) uint32_t*)ldsB, 16, 0, 0);
        }
        __syncthreads();

        #pragma unroll
        for (int kk = 0; kk < 64; kk += 32) {
            int fb = (kk + ((lane >> 4) << 3)) << 1;
            bf16x8_t af[4], bfr[4];
            #pragma unroll
            for (int i = 0; i < 4; ++i) {
                int row = wm + i * 16 + (lane & 15);
                int byteA = (row << 7) + (fb ^ ((row & 7) << 4));
                af[i] = *reinterpret_cast<const bf16x8_t*>(
                    reinterpret_cast<const char*>(As) + byteA);
                int col = wn + i * 16 + (lane & 15);
                int byteB = (col << 7) + (fb ^ ((col & 7) << 4));
                bfr[i] = *reinterpret_cast<const bf16x8_t*>(
                    reinterpret_cast<const char*>(Bs) + byteB);
            }
            #pragma unroll
            for (int i = 0; i < 4; ++i)
                #pragma unroll
                for (int j = 0; j < 4; ++j)
                    acc[i][j] = __builtin_amdgcn_mfma_f32_16x16x32_bf16(
                        af[i], bfr[j], acc[i][j], 0, 0, 0);
        }
        __syncthreads();
    }

    #pragma unroll
    for (int i = 0; i < 4; ++i) {
        int row0 = bm + wm + i * 16 + ((lane >> 4) << 2);
        #pragma unroll
        for (int j = 0; j < 4; ++j) {
            int col = bn + wn + j * 16 + (lane & 15);
            if (col >= N) continue;
            #pragma unroll
            for (int rg = 0; rg < 4; ++rg) {
                float v = acc[i][j][rg];
                int row = row0 + rg;
                if (col < 1024)       R_[(size_t)row * 1024 + col] = v;
                else if (col < 1536)  K_[(size_t)row * 512 + (col - 1024)] = v;
                else if (col < 2048)  V_[(size_t)row * 512 + (col - 1536)] = v;
                else if (col < 2112)  W1b[(size_t)row * 64 + (col - 2048)] = f2bf(tanhf(v));
                else if (col < 2176)  A1b[(size_t)row * 64 + (col - 2112)] = f2bf(v);
                else if (col < 2240)  V1b[(size_t)row * 64 + (col - 2176)] = f2bf(v);
                else                  G1b[(size_t)row * 192 + (col - 2240)] = f2bf(1.f / (1.f + expf(-v)));
            }
        }
    }
}

// ---------------------------------------------------------------------------
// bf16 MFMA GEMM (plain epilogue) for the output projection.
// ---------------------------------------------------------------------------
__global__ __launch_bounds__(256) void gemm_bf16(
    const uint16_t* __restrict__ A, const uint16_t* __restrict__ Bt,
    float* __restrict__ C, int M, int N, int K)
{
    __shared__ __align__(16) uint16_t As[128 * 64];
    __shared__ __align__(16) uint16_t Bs[128 * 64];
    int tid  = threadIdx.x;
    int lane = tid & 63, wid = tid >> 6;
    int wm = (wid >> 1) * 64, wn = (wid & 1) * 64;
    int bm = blockIdx.y * 128, bn = blockIdx.x * 128;

    f32x4_t acc[4][4];
    #pragma unroll
    for (int i = 0; i < 4; ++i)
        #pragma unroll
        for (int j = 0; j < 4; ++j)
            #pragma unroll
            for (int e = 0; e < 4; ++e) acc[i][j][e] = 0.f;

    int rowS[4], kbS[4];
    #pragma unroll
    for (int i = 0; i < 4; ++i) {
        int d = (i * 256 + tid) * 16;
        int row = d >> 7;
        int kb = (d & 127) ^ ((row & 7) << 4);
        rowS[i] = row; kbS[i] = kb >> 1;
    }

    for (int k0 = 0; k0 < K; k0 += 64) {
        #pragma unroll
        for (int i = 0; i < 4; ++i) {
            const uint16_t* srcA = A + (size_t)(bm + rowS[i]) * K + k0 + kbS[i];
            uint16_t* ldsA = As + (i * 256 + wid * 64) * 8;
            __builtin_amdgcn_global_load_lds(
                (const __attribute__((address_space(1))) uint32_t*)srcA,
                (__attribute__((address_space(3))) uint32_t*)ldsA, 16, 0, 0);
            int nr = bn + rowS[i];
            const uint16_t* srcB = Bt + (size_t)(nr < N ? nr : 0) * K + k0 + kbS[i];
            uint16_t* ldsB = Bs + (i * 256 + wid * 64) * 8;
            __builtin_amdgcn_global_load_lds(
                (const __attribute__((address_space(1))) uint32_t*)srcB,
                (__attribute__((address_space(3))) uint32_t*)ldsB, 16, 0, 0);
        }
        __syncthreads();

        #pragma unroll
        for (int kk = 0; kk < 64; kk += 32) {
            int fb = (kk + ((lane >> 4) << 3)) << 1;
            bf16x8_t af[4], bfr[4];
            #pragma unroll
            for (int i = 0; i < 4; ++i) {
                int row = wm + i * 16 + (lane & 15);
                int byteA = (row << 7) + (fb ^ ((row & 7) << 4));
                af[i] = *reinterpret_cast<const bf16x8_t*>(
                    reinterpret_cast<const char*>(As) + byteA);
                int col = wn + i * 16 + (lane & 15);
                int byteB = (col << 7) + (fb ^ ((col & 7) << 4));
                bfr[i] = *reinterpret_cast<const bf16x8_t*>(
                    reinterpret_cast<const char*>(Bs) + byteB);
            }
            #pragma unroll
            for (int i = 0; i < 4; ++i)
                #pragma unroll
                for (int j = 0; j < 4; ++j)
                    acc[i][j] = __builtin_amdgcn_mfma_f32_16x16x32_bf16(
                        af[i], bfr[j], acc[i][j], 0, 0, 0);
        }
        __syncthreads();
    }

    #pragma unroll
    for (int i = 0; i < 4; ++i) {
        int row0 = bm + wm + i * 16 + ((lane >> 4) << 2);
        #pragma unroll
        for (int j = 0; j < 4; ++j) {
            int col = bn + wn + j * 16 + (lane & 15);
            if (col >= N) continue;
            #pragma unroll
            for (int rg = 0; rg < 4; ++rg)
                C[(size_t)(row0 + rg) * N + col] = acc[i][j][rg];
        }
    }
}

// ---------------------------------------------------------------------------
// Stage-2 LoRA GEMMs as one fused MFMA kernel. 4 segments, INTERLEAVED.
// ---------------------------------------------------------------------------
__global__ __launch_bounds__(256) void lora2_mfma(
    const uint16_t* __restrict__ W1b, const uint16_t* __restrict__ A1b,
    const uint16_t* __restrict__ V1b, const uint16_t* __restrict__ G1b,
    const uint16_t* __restrict__ LW, const uint16_t* __restrict__ LA,
    const uint16_t* __restrict__ LV, const uint16_t* __restrict__ LG,
    const float* __restrict__ w0, const float* __restrict__ a0, const float* __restrict__ v0,
    const float* __restrict__ VRAW, const float* __restrict__ vfi,
    const float* __restrict__ ABUF,
    float* __restrict__ DEC, float* __restrict__ AARR,
    float* __restrict__ VFIN, float* __restrict__ GARR)
{
    int seg = blockIdx.x & 3;
    int bn = (blockIdx.x >> 2) * 128;
    int bm = blockIdx.y * 128;

    const uint16_t* A; const uint16_t* Bt; int K;
    if (seg == 0)      { A = W1b; Bt = LW; K = 64; }
    else if (seg == 1) { A = A1b; Bt = LA; K = 64; }
    else if (seg == 2) { A = V1b; Bt = LV; K = 64; }
    else               { A = G1b; Bt = LG; K = 192; }

    __shared__ __align__(16) uint16_t As[128 * 64];
    __shared__ __align__(16) uint16_t Bs[128 * 64];
    int tid  = threadIdx.x;
    int lane = tid & 63, wid = tid >> 6;
    int wm = (wid >> 1) * 64, wn = (wid & 1) * 64;

    f32x4_t acc[4][4];
    #pragma unroll
    for (int i = 0; i < 4; ++i)
        #pragma unroll
        for (int j = 0; j < 4; ++j)
            #pragma unroll
            for (int e = 0; e < 4; ++e) acc[i][j][e] = 0.f;

    int rowS[4], kbS[4];
    #pragma unroll
    for (int i = 0; i < 4; ++i) {
        int d = (i * 256 + tid) * 16;
        int row = d >> 7;
        int kb = (d & 127) ^ ((row & 7) << 4);
        rowS[i] = row; kbS[i] = kb >> 1;
    }

    for (int k0 = 0; k0 < K; k0 += 64) {
        #pragma unroll
        for (int i = 0; i < 4; ++i) {
            const uint16_t* srcA = A + (size_t)(bm + rowS[i]) * K + k0 + kbS[i];
            uint16_t* ldsA = As + (i * 256 + wid * 64) * 8;
            __builtin_amdgcn_global_load_lds(
                (const __attribute__((address_space(1))) uint32_t*)srcA,
                (__attribute__((address_space(3))) uint32_t*)ldsA, 16, 0, 0);
            const uint16_t* srcB = Bt + (size_t)(bn + rowS[i]) * K + k0 + kbS[i];
            uint16_t* ldsB = Bs + (i * 256 + wid * 64) * 8;
            __builtin_amdgcn_global_load_lds(
                (const __attribute__((address_space(1))) uint32_t*)srcB,
                (__attribute__((address_space(3))) uint32_t*)ldsB, 16, 0, 0);
        }
        __syncthreads();

        #pragma unroll
        for (int kk = 0; kk < 64; kk += 32) {
            int fb = (kk + ((lane >> 4) << 3)) << 1;
            bf16x8_t af[4], bfr[4];
            #pragma unroll
            for (int i = 0; i < 4; ++i) {
                int row = wm + i * 16 + (lane & 15);
                int byteA = (row << 7) + (fb ^ ((row & 7) << 4));
                af[i] = *reinterpret_cast<const bf16x8_t*>(
                    reinterpret_cast<const char*>(As) + byteA);
                int col = wn + i * 16 + (lane & 15);
                int byteB = (col << 7) + (fb ^ ((col & 7) << 4));
                bfr[i] = *reinterpret_cast<const bf16x8_t*>(
                    reinterpret_cast<const char*>(Bs) + byteB);
            }
            #pragma unroll
            for (int i = 0; i < 4; ++i)
                #pragma unroll
                for (int j = 0; j < 4; ++j)
                    acc[i][j] = __builtin_amdgcn_mfma_f32_16x16x32_bf16(
                        af[i], bfr[j], acc[i][j], 0, 0, 0);
        }
        __syncthreads();
    }

    #pragma unroll
    for (int i = 0; i < 4; ++i) {
        int row0 = bm + wm + i * 16 + ((lane >> 4) << 2);
        #pragma unroll
        for (int j = 0; j < 4; ++j) {
            int col = bn + wn + j * 16 + (lane & 15);
            #pragma unroll
            for (int rg = 0; rg < 4; ++rg) {
                float v = acc[i][j][rg];
                int row = row0 + rg;
                if (seg == 0) {
                    // exp(-exp(-softplus(-z)-0.5)) == exp(-e^{-0.5}*sigmoid(z))
                    float z = v + w0[col];
                    float sig = 1.f / (1.f + expf(-z));
                    DEC[(size_t)row * 1024 + col] = expf(-0.6065306597f * sig);
                } else if (seg == 1) {
                    float kk = -ABUF[(size_t)row * 512 + ((col >> 7) << 6) + (col & 63)];
                    AARR[(size_t)row * 1024 + col] = kk / (1.f + expf(-(v + a0[col])));
                } else if (seg == 2) {
                    float m = 1.f / (1.f + expf(-(v + v0[col])));
                    float vr = VRAW[(size_t)row * 512 + ((col >> 7) << 6) + (col & 63)];
                    float vf = vfi[(size_t)row * 1024 + col];
                    VFIN[(size_t)row * 1024 + col] = vr + (vf - vr) * m;
                } else {
                    GARR[(size_t)row * 1024 + col] = v;
                }
            }
        }
    }
}

// ---------------------------------------------------------------------------
// Fused RMS-norm + RoPE (R & K) + prep (kk -> ABUF, BON). cos/sin inline.
// ---------------------------------------------------------------------------
__global__ __launch_bounds__(64) void normrope_prep(
    float* __restrict__ RRAW, float* __restrict__ KRAW,
    float* __restrict__ ABUF,
    const float* __restrict__ rnw, const float* __restrict__ knw,
    const float* __restrict__ rk,
    float* __restrict__ BON)
{
    int blk = blockIdx.x;      // bt*8 + hk
    int hk = blk & 7;
    int bt = blk >> 3;
    int b = bt >> 10, t = bt & 1023;
    int lane = threadIdx.x;
    int fi = lane & 31;
    float invf = powf(1.0e6f, -(float)fi * (1.0f / 32.0f));
    float fr = (float)t * invf;
    float c = cosf(fr), s = sinf(fr);

    // ---- K head: norm + rope + kk ----
    size_t kidx = ((size_t)bt * 8 + hk) * 64 + lane;
    float k = KRAW[kidx];
    float ss = k * k;
    #pragma unroll
    for (int m = 1; m < 64; m <<= 1) ss += __shfl_xor(ss, m, 64);
    float kn = k * rsqrtf(ss * (1.f / 64.f) + 1e-6f) * knw[lane];
    float kp = __shfl_xor(kn, 32, 64);
    float kroped = fmaf(kn, c, ((lane < 32) ? -kp : kp) * s);
    KRAW[kidx] = kroped;

    float ss2 = kroped * kroped;
    #pragma unroll
    for (int m = 1; m < 64; m <<= 1) ss2 += __shfl_xor(ss2, m, 64);
    float kk = kroped / fmaxf(sqrtf(ss2), 1e-12f);
    ABUF[kidx] = -kk;

    // ---- R heads (2 per kv head): norm + rope + BON ----
    #pragma unroll
    for (int rep = 0; rep < 2; ++rep) {
        int h = hk * 2 + rep;
        size_t cidx = (size_t)bt * 1024 + h * 64 + lane;
        float r = RRAW[cidx];
        float ssr = r * r;
        #pragma unroll
        for (int m = 1; m < 64; m <<= 1) ssr += __shfl_xor(ssr, m, 64);
        float rn = r * rsqrtf(ssr * (1.f / 64.f) + 1e-6f) * rnw[lane];
        float rp = __shfl_xor(rn, 32, 64);
        float rroped = fmaf(rn, c, ((lane < 32) ? -rp : rp) * s);
        RRAW[cidx] = rroped;

        float bon = rroped * kroped * rk[h * 64 + lane];
        #pragma unroll
        for (int m = 1; m < 64; m <<= 1) bon += __shfl_xor(bon, m, 64);
        if (lane == 0) BON[((size_t)(b * 16 + h)) * 1024 + t] = bon;
    }
}

// ---------------------------------------------------------------------------
// wkv_pass1 (r10 structure — measured equilibrium): per-chunk zero-state
// scan, CL=32, ONE wave per chunk holding BOTH P and Z. Operand arrays
// stream through double-buffered LDS via global_load_lds with counted vmcnt;
// shared by both state updates (81 LDS reads/step). Epilogue writes P
// transposed+XOR-swizzled for pass2. NO occupancy clamp.
// Variants measured and rejected: full-readlane (r8: +90%), bf16-pack
// (r11: +95%), phase-A readlane (r13: +18%) — LDS-broadcast is the cheapest
// pipe for this dual-state formulation.
// ---------------------------------------------------------------------------
__global__ __launch_bounds__(64) void wkv_pass1(
    const float* __restrict__ R, const float* __restrict__ Kv,
    const float* __restrict__ Ab, const float* __restrict__ Bhat,
    const float* __restrict__ Dd, const float* __restrict__ Vv,
    float* __restrict__ Q, float* __restrict__ Y0,
    float* __restrict__ PLT, float* __restrict__ ZL)
{
    int blk = blockIdx.x;           // bh*NC + c
    int c   = blk & (NC - 1);
    int bh  = blk >> 5;
    int h   = bh & 15;
    int b   = bh >> 4;
    int hk  = h >> 1;
    int lane = threadIdx.x;
    int t0 = c * CL;

    size_t cb = ((size_t)(b * 1024 + t0)) * 1024 + h * 64;
    size_t kb = ((size_t)(b * 1024 + t0)) * 512 + hk * 64;
    size_t qb = (((size_t)bh) * 1024 + t0) * 64;

    __shared__ __align__(16) float sA[2][64], sB[2][64], sD[2][64],
                                   sR[2][64], sK[2][64], sV[2][64];

    float SP[64], SZ[64];
    #pragma unroll
    for (int j = 0; j < 64; ++j) { SP[j] = (j == lane) ? 1.f : 0.f; SZ[j] = 0.f; }

    auto stage = [&](int u, int buf) {
        stage64(Ab   + kb + (size_t)u * 512,  &sA[buf][0], lane);
        stage64(Bhat + cb + (size_t)u * 1024, &sB[buf][0], lane);
        stage64(Dd   + cb + (size_t)u * 1024, &sD[buf][0], lane);
        stage64(R    + cb + (size_t)u * 1024, &sR[buf][0], lane);
        stage64(Kv   + kb + (size_t)u * 512,  &sK[buf][0], lane);
        stage64(Vv   + cb + (size_t)u * 1024, &sV[buf][0], lane);
    };
    stage(0, 0);

    for (int u = 0; u < CL; ++u) {
        int un = (u + 1 < CL) ? u + 1 : u;
        stage(un, (u + 1) & 1);
        asm volatile("s_waitcnt vmcnt(6)" ::: "memory");
        int cur = u & 1;
        float v = sV[cur][lane];

        float pa0 = 0.f, pa1 = 0.f, za0 = 0.f, za1 = 0.f;
        #pragma unroll
        for (int jc = 0; jc < 16; ++jc) {
            float4 a4 = *reinterpret_cast<const float4*>(&sA[cur][jc * 4]);
            pa0 = fmaf(SP[jc*4+0], a4.x, pa0); za0 = fmaf(SZ[jc*4+0], a4.x, za0);
            pa1 = fmaf(SP[jc*4+1], a4.y, pa1); za1 = fmaf(SZ[jc*4+1], a4.y, za1);
            pa0 = fmaf(SP[jc*4+2], a4.z, pa0); za0 = fmaf(SZ[jc*4+2], a4.z, za0);
            pa1 = fmaf(SP[jc*4+3], a4.w, pa1); za1 = fmaf(SZ[jc*4+3], a4.w, za1);
        }
        float pa = pa0 + pa1;
        float za = za0 + za1;

        float q0 = 0.f, q1 = 0.f, y0a = 0.f, y1a = 0.f;
        #pragma unroll
        for (int jc = 0; jc < 16; ++jc) {
            float4 d4 = *reinterpret_cast<const float4*>(&sD[cur][jc * 4]);
            float4 b4 = *reinterpret_cast<const float4*>(&sB[cur][jc * 4]);
            float4 k4 = *reinterpret_cast<const float4*>(&sK[cur][jc * 4]);
            float4 r4 = *reinterpret_cast<const float4*>(&sR[cur][jc * 4]);
            SP[jc*4+0] = fmaf(SP[jc*4+0], d4.x, pa * b4.x); q0  = fmaf(SP[jc*4+0], r4.x, q0);
            SZ[jc*4+0] = fmaf(SZ[jc*4+0], d4.x, fmaf(za, b4.x, v * k4.x)); y0a = fmaf(SZ[jc*4+0], r4.x, y0a);
            SP[jc*4+1] = fmaf(SP[jc*4+1], d4.y, pa * b4.y); q1  = fmaf(SP[jc*4+1], r4.y, q1);
            SZ[jc*4+1] = fmaf(SZ[jc*4+1], d4.y, fmaf(za, b4.y, v * k4.y)); y1a = fmaf(SZ[jc*4+1], r4.y, y1a);
            SP[jc*4+2] = fmaf(SP[jc*4+2], d4.z, pa * b4.z); q0  = fmaf(SP[jc*4+2], r4.z, q0);
            SZ[jc*4+2] = fmaf(SZ[jc*4+2], d4.z, fmaf(za, b4.z, v * k4.z)); y0a = fmaf(SZ[jc*4+2], r4.z, y0a);
            SP[jc*4+3] = fmaf(SP[jc*4+3], d4.w, pa * b4.w); q1  = fmaf(SP[jc*4+3], r4.w, q1);
            SZ[jc*4+3] = fmaf(SZ[jc*4+3], d4.w, fmaf(za, b4.w, v * k4.w)); y1a = fmaf(SZ[jc*4+3], r4.w, y1a);
        }
        Q[qb + (size_t)u * 64 + lane]    = q0 + q1;
        Y0[cb + (size_t)u * 1024 + lane] = y0a + y1a;
    }

    // P transposed + swizzled: PLT[col*64 + (row ^ ((col&7)<<2))] = P[row][col]
    size_t pbT = (size_t)blk * 4096;
    #pragma unroll
    for (int j = 0; j < 64; ++j)
        PLT[pbT + j * 64 + (lane ^ ((j & 7) << 2))] = SP[j];
    size_t pb = pbT + (size_t)lane * 64;
    #pragma unroll
    for (int j = 0; j < 64; j += 4)
        *reinterpret_cast<float4*>(&ZL[pb + j]) =
            make_float4(SZ[j], SZ[j + 1], SZ[j + 2], SZ[j + 3]);
}

// ---------------------------------------------------------------------------
// wkv_pass2 (r8 version): chunk-state propagation, row-parallel. 256 blocks =
// (bh, 16-row group); 4 waves x 4 rows, lane = column. S rows in VGPRs;
// row-broadcast via readlane; P staged column-major+swizzled to LDS.
// ---------------------------------------------------------------------------
__global__ __launch_bounds__(256) void wkv_pass2(
    const float* __restrict__ PLT, float* ZLio)
{
    int blk = blockIdx.x;        // bh*4 + rg
    int rg  = blk & 3;
    int bh  = blk >> 2;
    int tid = threadIdx.x, lane = tid & 63, wv = tid >> 6;

    __shared__ __align__(16) float Pld[2][4096];
    __shared__ __align__(16) float Zld[2][1024];

    float S0 = 0.f, S1 = 0.f, S2 = 0.f, S3 = 0.f;

    auto stage = [&](int cc, int buf) {
        size_t pbase = ((size_t)bh * NC + cc) * 4096;
        #pragma unroll
        for (int i = 0; i < 4; ++i) {
            const float* src = PLT + pbase + (size_t)(i * 256 + tid) * 4;
            float* dst = &Pld[buf][(i * 256 + wv * 64) * 4];
            __builtin_amdgcn_global_load_lds(
                (const __attribute__((address_space(1))) uint32_t*)src,
                (__attribute__((address_space(3))) uint32_t*)dst, 16, 0, 0);
        }
        const float* zsrc = ZLio + pbase + (size_t)rg * 1024 + (size_t)tid * 4;
        float* zdst = &Zld[buf][wv * 256];
        __builtin_amdgcn_global_load_lds(
            (const __attribute__((address_space(1))) uint32_t*)zsrc,
            (__attribute__((address_space(3))) uint32_t*)zdst, 16, 0, 0);
    };

    stage(0, 0);

    for (int cc = 0; cc < NC; ++cc) {
        int cur = cc & 1;
        if (cc + 1 < NC) {
            stage(cc + 1, cur ^ 1);
            asm volatile("s_waitcnt vmcnt(5)" ::: "memory");
        } else {
            asm volatile("s_waitcnt vmcnt(0)" ::: "memory");
        }
        __syncthreads();

        size_t sb = ((size_t)bh * NC + cc) * 4096 + (size_t)(rg * 16 + wv * 4) * 64 + lane;
        ZLio[sb]       = S0;
        ZLio[sb + 64]  = S1;
        ZLio[sb + 128] = S2;
        ZLio[sb + 192] = S3;
        if (cc == NC - 1) break;

        int zb = (wv * 4) * 64 + lane;
        float acc0 = Zld[cur][zb],       acc1 = Zld[cur][zb + 64],
              acc2 = Zld[cur][zb + 128], acc3 = Zld[cur][zb + 192];
        const float* pcol = &Pld[cur][lane * 64];
        int swz = (lane & 7) << 2;
        #pragma unroll
        for (int m4 = 0; m4 < 64; m4 += 4) {
            float4 p4 = *reinterpret_cast<const float4*>(&pcol[m4 ^ swz]);
            #pragma unroll
            for (int s = 0; s < 4; ++s) {
                float pv = (&p4.x)[s];
                acc0 = fmaf(rlane(S0, m4 + s), pv, acc0);
                acc1 = fmaf(rlane(S1, m4 + s), pv, acc1);
                acc2 = fmaf(rlane(S2, m4 + s), pv, acc2);
                acc3 = fmaf(rlane(S3, m4 + s), pv, acc3);
            }
        }
        S0 = acc0; S1 = acc1; S2 = acc2; S3 = acc3;
        __syncthreads();
    }
}

// ---------------------------------------------------------------------------
// wkv_pass3: y = (y0 + Sstart.q + bon*v) * g -> bf16 for the Wo GEMM.
// ---------------------------------------------------------------------------
__global__ __launch_bounds__(64) void wkv_pass3(
    const float* __restrict__ SST, const float* __restrict__ Q,
    const float* __restrict__ Vv, const float* __restrict__ G,
    const float* __restrict__ BON, const float* __restrict__ Y0,
    uint16_t* __restrict__ Yb)
{
    int blk = blockIdx.x;   // bh*NC + c
    int c = blk & (NC - 1), bh = blk >> 5, h = bh & 15, b = bh >> 4;
    int lane = threadIdx.x;
    int t0 = c * CL;

    __shared__ __align__(16) float qs[2][64];
    __shared__ float bons[CL];
    if (lane < CL) bons[lane] = BON[((size_t)bh) * 1024 + t0 + lane];

    float S[64];
    size_t sb = ((size_t)blk) * 4096 + (size_t)lane * 64;
    #pragma unroll
    for (int jc = 0; jc < 16; ++jc) {
        float4 s4 = *reinterpret_cast<const float4*>(&SST[sb + jc * 4]);
        S[jc*4+0] = s4.x; S[jc*4+1] = s4.y; S[jc*4+2] = s4.z; S[jc*4+3] = s4.w;
    }

    size_t cb = ((size_t)(b * 1024 + t0)) * 1024 + h * 64 + lane;
    size_t qbase = (((size_t)bh) * 1024 + t0) * 64;

    stage64(Q + qbase, &qs[0][0], lane);
    for (int u = 0; u < CL; ++u) {
        int un = (u + 1 < CL) ? u + 1 : u;
        stage64(Q + qbase + (size_t)un * 64, &qs[(u + 1) & 1][0], lane);
        asm volatile("s_waitcnt vmcnt(1)" ::: "memory");
        int cur = u & 1;

        float d0 = 0.f, d1 = 0.f, d2 = 0.f, d3 = 0.f;
        #pragma unroll
        for (int jc = 0; jc < 16; ++jc) {
            float4 q4 = *reinterpret_cast<const float4*>(&qs[cur][jc * 4]);
            d0 = fmaf(S[jc*4+0], q4.x, d0);
            d1 = fmaf(S[jc*4+1], q4.y, d1);
            d2 = fmaf(S[jc*4+2], q4.z, d2);
            d3 = fmaf(S[jc*4+3], q4.w, d3);
        }
        float dot = (d0 + d1) + (d2 + d3);
        float y0 = Y0[cb + (size_t)u * 1024];
        float vc = Vv[cb + (size_t)u * 1024];
        float gc = G[cb + (size_t)u * 1024];
        float bon = bons[u];
        Yb[cb + (size_t)u * 1024] = f2bf((y0 + dot + bon * vc) * gc);
    }
}

// ---------------------------------------------------------------------------
extern "C" void kernel_launch(void* const* d_in, const int* in_sizes, int n_in,
                              void* d_out, int out_size, void* d_ws, size_t ws_size,
                              hipStream_t stream)
{
    const float* x   = (const float*)d_in[0];
    const float* vfi = (const float*)d_in[1];
    const float* Wr  = (const float*)d_in[2];
    const float* Wk  = (const float*)d_in[3];
    const float* Wv  = (const float*)d_in[4];
    const float* Wo  = (const float*)d_in[5];
    const float* w0  = (const float*)d_in[6];
    const float* w1  = (const float*)d_in[7];
    const float* w2  = (const float*)d_in[8];
    const float* a0  = (const float*)d_in[9];
    const float* a1  = (const float*)d_in[10];
    const float* a2  = (const float*)d_in[11];
    const float* v0  = (const float*)d_in[12];
    const float* v1  = (const float*)d_in[13];
    const float* v2  = (const float*)d_in[14];
    const float* g1  = (const float*)d_in[15];
    const float* g2  = (const float*)d_in[16];
    const float* rk  = (const float*)d_in[17];
    const float* rnw = (const float*)d_in[18];
    const float* knw = (const float*)d_in[19];

    float* ws = (float*)d_ws;
    size_t o = 0;
    float* RRAW = ws + o; o += (size_t)MT * 1024;
    float* KRAW = ws + o; o += (size_t)MT * 512;
    float* VRAW = ws + o; o += (size_t)MT * 512;
    float* DEC  = ws + o; o += (size_t)MT * 1024;
    float* AARR = ws + o; o += (size_t)MT * 1024;
    float* GARR = ws + o; o += (size_t)MT * 1024;
    float* VFIN = ws + o; o += (size_t)MT * 1024;
    float* YARR = ws + o; o += (size_t)MT * 1024;  // y0 from pass1
    float* ABUF = ws + o; o += (size_t)MT * 512;
    float* QBUF = ws + o; o += (size_t)MT * 1024;
    float* PLB  = ws + o; o += (size_t)(Bb * Hh * NC) * 4096;  // 32 MB (transposed+swizzled)
    float* ZLB  = ws + o; o += (size_t)(Bb * Hh * NC) * 4096;  // 32 MB (becomes SST)
    float* BON  = ws + o; o += (size_t)64 * 1024;
    uint16_t* XB   = (uint16_t*)(ws + o); o += (size_t)MT * 512;
    uint16_t* WCAT = (uint16_t*)(ws + o); o += (size_t)NCAT * 512;
    uint16_t* WoT  = (uint16_t*)(ws + o); o += (size_t)1024 * 512;
    uint16_t* W1b  = (uint16_t*)(ws + o); o += (size_t)MT * 32;   // [MT][64] bf16
    uint16_t* A1b  = (uint16_t*)(ws + o); o += (size_t)MT * 32;
    uint16_t* V1b  = (uint16_t*)(ws + o); o += (size_t)MT * 32;   // [MT][64], cols 32+ zero
    uint16_t* G1b  = (uint16_t*)(ws + o); o += (size_t)MT * 96;   // [MT][192], cols 160+ zero
    uint16_t* LW   = (uint16_t*)(ws + o); o += (size_t)1024 * 32; // w2^T [1024][64]
    uint16_t* LA   = (uint16_t*)(ws + o); o += (size_t)1024 * 32;
    uint16_t* LV   = (uint16_t*)(ws + o); o += (size_t)1024 * 32;
    uint16_t* LG   = (uint16_t*)(ws + o); o += (size_t)1024 * 96; // g2^T [1024][192]
    uint16_t* YB = XB;          // alias: XB dead after stage-1 GEMM

    conv_copy_kernel<<<dim3(MT * 1024 / 4 / 256), dim3(256), 0, stream>>>(
        x, XB, (const float4*)vfi, (float4*)((float*)d_out + (size_t)MT * 1024), MT * 1024 / 4);
    transpose_all_kernel<<<dim3(32, 32, 12), dim3(256), 0, stream>>>(
        Wr, Wk, Wv, w1, a1, v1, g1, Wo, w2, a2, v2, g2, WCAT, WoT, LW, LA, LV, LG);

    dim3 blk(256);

    // stage 1: all projections in one bf16 MFMA GEMM (N = 2432)
    gemm_bf16_proj<<<dim3(NCAT / 128, MT / 128), blk, 0, stream>>>(
        XB, WCAT, MT, NCAT, 1024, RRAW, KRAW, VRAW, W1b, A1b, V1b, G1b);

    // stage 2: fused RMS norm + RoPE + kk/BON prep (before lora2: it feeds ABUF)
    normrope_prep<<<dim3(MT * HKVn), dim3(64), 0, stream>>>(
        RRAW, KRAW, ABUF, rnw, knw, rk, BON);

    // stage 3: all LoRA second matmuls in one fused MFMA launch (interleaved segs)
    lora2_mfma<<<dim3(32, MT / 128), blk, 0, stream>>>(
        W1b, A1b, V1b, G1b, LW, LA, LV, LG, w0, a0, v0, VRAW, vfi, ABUF,
        DEC, AARR, VFIN, GARR);

    // stage 4: chunk-parallel WKV scan
    wkv_pass1<<<dim3(Bb * Hh * NC), dim3(64), 0, stream>>>(
        RRAW, KRAW, ABUF, AARR, DEC, VFIN, QBUF, YARR, PLB, ZLB);
    wkv_pass2<<<dim3(Bb * Hh * 4), dim3(256), 0, stream>>>(PLB, ZLB);
    wkv_pass3<<<dim3(Bb * Hh * NC), dim3(64), 0, stream>>>(
        ZLB, QBUF, VFIN, GARR, BON, YARR, YB);

    // stage 5: out = (y*g) @ Wo (bf16 MFMA)
    gemm_bf16<<<dim3(1024 / 128, MT / 128), blk, 0, stream>>>(
        YB, WoT, (float*)d_out, MT, 1024, 1024);
}

// Round 15
// 392.044 us; speedup vs baseline: 1.0466x; 1.0326x over previous
//
#include <hip/hip_runtime.h>
#include <math.h>
#include <stdint.h>

// Problem constants
#define Bb   4
#define Tt   1024
#define Cc   1024
#define Hh   16
#define HKVn 8
#define Nn   64
#define MT   (Bb*Tt)
#define NC   32      // chunks per sequence
#define CL   32      // chunk length
#define NCAT 2432    // 1024+512+512+64+64+(32+32pad)+(160+32pad) -> 19*128

typedef __bf16 bf16x8_t __attribute__((ext_vector_type(8)));
typedef float  f32x4_t  __attribute__((ext_vector_type(4)));

__device__ __forceinline__ uint16_t f2bf(float f) {
    uint32_t u = __float_as_uint(f);
    uint32_t r = (u + 0x7fffu + ((u >> 16) & 1u)) >> 16;
    return (uint16_t)r;
}

// wave-broadcast: value held by lane l (VALU pipe, not LDS)
__device__ __forceinline__ float rlane(float v, int l) {
    return __uint_as_float(__builtin_amdgcn_readlane(__float_as_uint(v), l));
}

// async-stage one 64-float wave-uniform array into LDS (lane i -> l[i])
__device__ __forceinline__ void stage64(const float* g, float* l, int lane) {
    __builtin_amdgcn_global_load_lds(
        (const __attribute__((address_space(1))) uint32_t*)(g + lane),
        (__attribute__((address_space(3))) uint32_t*)l, 4, 0, 0);
}

// ---------------------------------------------------------------------------
// All weight transposes + (z=12) x->bf16 convert + v_first copy, one launch.
// ---------------------------------------------------------------------------
__global__ __launch_bounds__(256) void transpose_all_kernel(
    const float* __restrict__ Wr, const float* __restrict__ Wk, const float* __restrict__ Wv,
    const float* __restrict__ w1, const float* __restrict__ a1, const float* __restrict__ v1,
    const float* __restrict__ g1, const float* __restrict__ Wo,
    const float* __restrict__ w2, const float* __restrict__ a2,
    const float* __restrict__ v2, const float* __restrict__ g2,
    uint16_t* __restrict__ WCAT, uint16_t* __restrict__ WoT,
    uint16_t* __restrict__ LW, uint16_t* __restrict__ LA,
    uint16_t* __restrict__ LV, uint16_t* __restrict__ LG,
    const float* __restrict__ x, uint16_t* __restrict__ xb,
    const float4* __restrict__ vfi, float4* __restrict__ out2)
{
    int z = blockIdx.z;
    if (z == 12) {
        // x -> bf16 + v_first passthrough (4 float4s per thread, grid-stride)
        int bid = blockIdx.y * 32 + blockIdx.x;
        int tid0 = bid * 256 + threadIdx.x;
        #pragma unroll
        for (int it = 0; it < 4; ++it) {
            int i = tid0 + it * (1024 * 256);
            float4 v = reinterpret_cast<const float4*>(x)[i];
            ushort4 o;
            o.x = f2bf(v.x); o.y = f2bf(v.y); o.z = f2bf(v.z); o.w = f2bf(v.w);
            reinterpret_cast<ushort4*>(xb)[i] = o;
            out2[i] = vfi[i];
        }
        return;
    }
    const float* W; int Nsrc, Ndst, Ksrc, Kout, off; uint16_t* out;
    switch (z) {
        case 0:  W = Wr; Nsrc = 1024; Ndst = 1024; Ksrc = 1024; Kout = 1024; off = 0;    out = WCAT; break;
        case 1:  W = Wk; Nsrc = 512;  Ndst = 512;  Ksrc = 1024; Kout = 1024; off = 1024; out = WCAT; break;
        case 2:  W = Wv; Nsrc = 512;  Ndst = 512;  Ksrc = 1024; Kout = 1024; off = 1536; out = WCAT; break;
        case 3:  W = w1; Nsrc = 64;   Ndst = 64;   Ksrc = 1024; Kout = 1024; off = 2048; out = WCAT; break;
        case 4:  W = a1; Nsrc = 64;   Ndst = 64;   Ksrc = 1024; Kout = 1024; off = 2112; out = WCAT; break;
        case 5:  W = v1; Nsrc = 32;   Ndst = 64;   Ksrc = 1024; Kout = 1024; off = 2176; out = WCAT; break;
        case 6:  W = g1; Nsrc = 160;  Ndst = 192;  Ksrc = 1024; Kout = 1024; off = 2240; out = WCAT; break;
        case 7:  W = Wo; Nsrc = 1024; Ndst = 1024; Ksrc = 1024; Kout = 1024; off = 0;    out = WoT;  break;
        case 8:  W = w2; Nsrc = 1024; Ndst = 1024; Ksrc = 64;   Kout = 64;   off = 0;    out = LW;   break;
        case 9:  W = a2; Nsrc = 1024; Ndst = 1024; Ksrc = 64;   Kout = 64;   off = 0;    out = LA;   break;
        case 10: W = v2; Nsrc = 1024; Ndst = 1024; Ksrc = 32;   Kout = 64;   off = 0;    out = LV;   break;
        default: W = g2; Nsrc = 1024; Ndst = 1024; Ksrc = 160;  Kout = 192;  off = 0;    out = LG;   break;
    }
    int n0 = blockIdx.x * 32, k0 = blockIdx.y * 32;
    if (n0 >= Ndst || k0 >= Kout) return;
    __shared__ float tile[32][33];
    int tx = threadIdx.x & 31, ty = threadIdx.x >> 5; // 32 x 8
    #pragma unroll
    for (int i = 0; i < 32; i += 8) {
        int k = k0 + ty + i, n = n0 + tx;
        tile[ty + i][tx] = (k < Ksrc && n < Nsrc) ? W[(size_t)k * Nsrc + n] : 0.f;
    }
    __syncthreads();
    #pragma unroll
    for (int i = 0; i < 32; i += 8) {
        int n = n0 + ty + i, k = k0 + tx;
        if (n < Ndst) out[(size_t)(off + n) * Kout + k] = f2bf(tile[tx][ty + i]);
    }
}

// ---------------------------------------------------------------------------
// Fused stage-1 projection GEMM: C[M][2432] = XB[M][1024] @ WCAT^T.
// ---------------------------------------------------------------------------
__global__ __launch_bounds__(256) void gemm_bf16_proj(
    const uint16_t* __restrict__ A, const uint16_t* __restrict__ Bt,
    int M, int N, int K,
    float* __restrict__ R_, float* __restrict__ K_, float* __restrict__ V_,
    uint16_t* __restrict__ W1b, uint16_t* __restrict__ A1b,
    uint16_t* __restrict__ V1b, uint16_t* __restrict__ G1b)
{
    __shared__ __align__(16) uint16_t As[128 * 64];
    __shared__ __align__(16) uint16_t Bs[128 * 64];
    int tid  = threadIdx.x;
    int lane = tid & 63, wid = tid >> 6;
    int wm = (wid >> 1) * 64, wn = (wid & 1) * 64;
    int bm = blockIdx.y * 128, bn = blockIdx.x * 128;

    f32x4_t acc[4][4];
    #pragma unroll
    for (int i = 0; i < 4; ++i)
        #pragma unroll
        for (int j = 0; j < 4; ++j)
            #pragma unroll
            for (int e = 0; e < 4; ++e) acc[i][j][e] = 0.f;

    int rowS[4], kbS[4];
    #pragma unroll
    for (int i = 0; i < 4; ++i) {
        int d = (i * 256 + tid) * 16;
        int row = d >> 7;
        int kb = (d & 127) ^ ((row & 7) << 4);
        rowS[i] = row; kbS[i] = kb >> 1;
    }

    for (int k0 = 0; k0 < K; k0 += 64) {
        #pragma unroll
        for (int i = 0; i < 4; ++i) {
            const uint16_t* srcA = A + (size_t)(bm + rowS[i]) * K + k0 + kbS[i];
            uint16_t* ldsA = As + (i * 256 + wid * 64) * 8;
            __builtin_amdgcn_global_load_lds(
                (const __attribute__((address_space(1))) uint32_t*)srcA,
                (__attribute__((address_space(3))) uint32_t*)ldsA, 16, 0, 0);
            int nr = bn + rowS[i];
            const uint16_t* srcB = Bt + (size_t)(nr < N ? nr : 0) * K + k0 + kbS[i];
            uint16_t* ldsB = Bs + (i * 256 + wid * 64) * 8;
            __builtin_amdgcn_global_load_lds(
                (const __attribute__((address_space(1))) uint32_t*)srcB,
                (__attribute__((address_space(3))) uint32_t*)ldsB, 16, 0, 0);
        }
        __syncthreads();

        #pragma unroll
        for (int kk = 0; kk < 64; kk += 32) {
            int fb = (kk + ((lane >> 4) << 3)) << 1;
            bf16x8_t af[4], bfr[4];
            #pragma unroll
            for (int i = 0; i < 4; ++i) {
                int row = wm + i * 16 + (lane & 15);
                int byteA = (row << 7) + (fb ^ ((row & 7) << 4));
                af[i] = *reinterpret_cast<const bf16x8_t*>(
                    reinterpret_cast<const char*>(As) + byteA);
                int col = wn + i * 16 + (lane & 15);
                int byteB = (col << 7) + (fb ^ ((col & 7) << 4));
                bfr[i] = *reinterpret_cast<const bf16x8_t*>(
                    reinterpret_cast<const char*>(Bs) + byteB);
            }
            #pragma unroll
            for (int i = 0; i < 4; ++i)
                #pragma unroll
                for (int j = 0; j < 4; ++j)
                    acc[i][j] = __builtin_amdgcn_mfma_f32_16x16x32_bf16(
                        af[i], bfr[j], acc[i][j], 0, 0, 0);
        }
        __syncthreads();
    }

    #pragma unroll
    for (int i = 0; i < 4; ++i) {
        int row0 = bm + wm + i * 16 + ((lane >> 4) << 2);
        #pragma unroll
        for (int j = 0; j < 4; ++j) {
            int col = bn + wn + j * 16 + (lane & 15);
            if (col >= N) continue;
            #pragma unroll
            for (int rg = 0; rg < 4; ++rg) {
                float v = acc[i][j][rg];
                int row = row0 + rg;
                if (col < 1024)       R_[(size_t)row * 1024 + col] = v;
                else if (col < 1536)  K_[(size_t)row * 512 + (col - 1024)] = v;
                else if (col < 2048)  V_[(size_t)row * 512 + (col - 1536)] = v;
                else if (col < 2112)  W1b[(size_t)row * 64 + (col - 2048)] = f2bf(tanhf(v));
                else if (col < 2176)  A1b[(size_t)row * 64 + (col - 2112)] = f2bf(v);
                else if (col < 2240)  V1b[(size_t)row * 64 + (col - 2176)] = f2bf(v);
                else                  G1b[(size_t)row * 192 + (col - 2240)] = f2bf(1.f / (1.f + expf(-v)));
            }
        }
    }
}

// ---------------------------------------------------------------------------
// bf16 MFMA GEMM (plain epilogue) for the output projection.
// ---------------------------------------------------------------------------
__global__ __launch_bounds__(256) void gemm_bf16(
    const uint16_t* __restrict__ A, const uint16_t* __restrict__ Bt,
    float* __restrict__ C, int M, int N, int K)
{
    __shared__ __align__(16) uint16_t As[128 * 64];
    __shared__ __align__(16) uint16_t Bs[128 * 64];
    int tid  = threadIdx.x;
    int lane = tid & 63, wid = tid >> 6;
    int wm = (wid >> 1) * 64, wn = (wid & 1) * 64;
    int bm = blockIdx.y * 128, bn = blockIdx.x * 128;

    f32x4_t acc[4][4];
    #pragma unroll
    for (int i = 0; i < 4; ++i)
        #pragma unroll
        for (int j = 0; j < 4; ++j)
            #pragma unroll
            for (int e = 0; e < 4; ++e) acc[i][j][e] = 0.f;

    int rowS[4], kbS[4];
    #pragma unroll
    for (int i = 0; i < 4; ++i) {
        int d = (i * 256 + tid) * 16;
        int row = d >> 7;
        int kb = (d & 127) ^ ((row & 7) << 4);
        rowS[i] = row; kbS[i] = kb >> 1;
    }

    for (int k0 = 0; k0 < K; k0 += 64) {
        #pragma unroll
        for (int i = 0; i < 4; ++i) {
            const uint16_t* srcA = A + (size_t)(bm + rowS[i]) * K + k0 + kbS[i];
            uint16_t* ldsA = As + (i * 256 + wid * 64) * 8;
            __builtin_amdgcn_global_load_lds(
                (const __attribute__((address_space(1))) uint32_t*)srcA,
                (__attribute__((address_space(3))) uint32_t*)ldsA, 16, 0, 0);
            int nr = bn + rowS[i];
            const uint16_t* srcB = Bt + (size_t)(nr < N ? nr : 0) * K + k0 + kbS[i];
            uint16_t* ldsB = Bs + (i * 256 + wid * 64) * 8;
            __builtin_amdgcn_global_load_lds(
                (const __attribute__((address_space(1))) uint32_t*)srcB,
                (__attribute__((address_space(3))) uint32_t*)ldsB, 16, 0, 0);
        }
        __syncthreads();

        #pragma unroll
        for (int kk = 0; kk < 64; kk += 32) {
            int fb = (kk + ((lane >> 4) << 3)) << 1;
            bf16x8_t af[4], bfr[4];
            #pragma unroll
            for (int i = 0; i < 4; ++i) {
                int row = wm + i * 16 + (lane & 15);
                int byteA = (row << 7) + (fb ^ ((row & 7) << 4));
                af[i] = *reinterpret_cast<const bf16x8_t*>(
                    reinterpret_cast<const char*>(As) + byteA);
                int col = wn + i * 16 + (lane & 15);
                int byteB = (col << 7) + (fb ^ ((col & 7) << 4));
                bfr[i] = *reinterpret_cast<const bf16x8_t*>(
                    reinterpret_cast<const char*>(Bs) + byteB);
            }
            #pragma unroll
            for (int i = 0; i < 4; ++i)
                #pragma unroll
                for (int j = 0; j < 4; ++j)
                    acc[i][j] = __builtin_amdgcn_mfma_f32_16x16x32_bf16(
                        af[i], bfr[j], acc[i][j], 0, 0, 0);
        }
        __syncthreads();
    }

    #pragma unroll
    for (int i = 0; i < 4; ++i) {
        int row0 = bm + wm + i * 16 + ((lane >> 4) << 2);
        #pragma unroll
        for (int j = 0; j < 4; ++j) {
            int col = bn + wn + j * 16 + (lane & 15);
            if (col >= N) continue;
            #pragma unroll
            for (int rg = 0; rg < 4; ++rg)
                C[(size_t)(row0 + rg) * N + col] = acc[i][j][rg];
        }
    }
}

// ---------------------------------------------------------------------------
// Stage-2 LoRA GEMMs as one fused MFMA kernel. 4 segments, INTERLEAVED.
// ---------------------------------------------------------------------------
__global__ __launch_bounds__(256) void lora2_mfma(
    const uint16_t* __restrict__ W1b, const uint16_t* __restrict__ A1b,
    const uint16_t* __restrict__ V1b, const uint16_t* __restrict__ G1b,
    const uint16_t* __restrict__ LW, const uint16_t* __restrict__ LA,
    const uint16_t* __restrict__ LV, const uint16_t* __restrict__ LG,
    const float* __restrict__ w0, const float* __restrict__ a0, const float* __restrict__ v0,
    const float* __restrict__ VRAW, const float* __restrict__ vfi,
    const float* __restrict__ ABUF,
    float* __restrict__ DEC, float* __restrict__ AARR,
    float* __restrict__ VFIN, float* __restrict__ GARR)
{
    int seg = blockIdx.x & 3;
    int bn = (blockIdx.x >> 2) * 128;
    int bm = blockIdx.y * 128;

    const uint16_t* A; const uint16_t* Bt; int K;
    if (seg == 0)      { A = W1b; Bt = LW; K = 64; }
    else if (seg == 1) { A = A1b; Bt = LA; K = 64; }
    else if (seg == 2) { A = V1b; Bt = LV; K = 64; }
    else               { A = G1b; Bt = LG; K = 192; }

    __shared__ __align__(16) uint16_t As[128 * 64];
    __shared__ __align__(16) uint16_t Bs[128 * 64];
    int tid  = threadIdx.x;
    int lane = tid & 63, wid = tid >> 6;
    int wm = (wid >> 1) * 64, wn = (wid & 1) * 64;

    f32x4_t acc[4][4];
    #pragma unroll
    for (int i = 0; i < 4; ++i)
        #pragma unroll
        for (int j = 0; j < 4; ++j)
            #pragma unroll
            for (int e = 0; e < 4; ++e) acc[i][j][e] = 0.f;

    int rowS[4], kbS[4];
    #pragma unroll
    for (int i = 0; i < 4; ++i) {
        int d = (i * 256 + tid) * 16;
        int row = d >> 7;
        int kb = (d & 127) ^ ((row & 7) << 4);
        rowS[i] = row; kbS[i] = kb >> 1;
    }

    for (int k0 = 0; k0 < K; k0 += 64) {
        #pragma unroll
        for (int i = 0; i < 4; ++i) {
            const uint16_t* srcA = A + (size_t)(bm + rowS[i]) * K + k0 + kbS[i];
            uint16_t* ldsA = As + (i * 256 + wid * 64) * 8;
            __builtin_amdgcn_global_load_lds(
                (const __attribute__((address_space(1))) uint32_t*)srcA,
                (__attribute__((address_space(3))) uint32_t*)ldsA, 16, 0, 0);
            const uint16_t* srcB = Bt + (size_t)(bn + rowS[i]) * K + k0 + kbS[i];
            uint16_t* ldsB = Bs + (i * 256 + wid * 64) * 8;
            __builtin_amdgcn_global_load_lds(
                (const __attribute__((address_space(1))) uint32_t*)srcB,
                (__attribute__((address_space(3))) uint32_t*)ldsB, 16, 0, 0);
        }
        __syncthreads();

        #pragma unroll
        for (int kk = 0; kk < 64; kk += 32) {
            int fb = (kk + ((lane >> 4) << 3)) << 1;
            bf16x8_t af[4], bfr[4];
            #pragma unroll
            for (int i = 0; i < 4; ++i) {
                int row = wm + i * 16 + (lane & 15);
                int byteA = (row << 7) + (fb ^ ((row & 7) << 4));
                af[i] = *reinterpret_cast<const bf16x8_t*>(
                    reinterpret_cast<const char*>(As) + byteA);
                int col = wn + i * 16 + (lane & 15);
                int byteB = (col << 7) + (fb ^ ((col & 7) << 4));
                bfr[i] = *reinterpret_cast<const bf16x8_t*>(
                    reinterpret_cast<const char*>(Bs) + byteB);
            }
            #pragma unroll
            for (int i = 0; i < 4; ++i)
                #pragma unroll
                for (int j = 0; j < 4; ++j)
                    acc[i][j] = __builtin_amdgcn_mfma_f32_16x16x32_bf16(
                        af[i], bfr[j], acc[i][j], 0, 0, 0);
        }
        __syncthreads();
    }

    #pragma unroll
    for (int i = 0; i < 4; ++i) {
        int row0 = bm + wm + i * 16 + ((lane >> 4) << 2);
        #pragma unroll
        for (int j = 0; j < 4; ++j) {
            int col = bn + wn + j * 16 + (lane & 15);
            #pragma unroll
            for (int rg = 0; rg < 4; ++rg) {
                float v = acc[i][j][rg];
                int row = row0 + rg;
                if (seg == 0) {
                    // exp(-exp(-softplus(-z)-0.5)) == exp(-e^{-0.5}*sigmoid(z))
                    float z = v + w0[col];
                    float sig = 1.f / (1.f + expf(-z));
                    DEC[(size_t)row * 1024 + col] = expf(-0.6065306597f * sig);
                } else if (seg == 1) {
                    float kk = -ABUF[(size_t)row * 512 + ((col >> 7) << 6) + (col & 63)];
                    AARR[(size_t)row * 1024 + col] = kk / (1.f + expf(-(v + a0[col])));
                } else if (seg == 2) {
                    float m = 1.f / (1.f + expf(-(v + v0[col])));
                    float vr = VRAW[(size_t)row * 512 + ((col >> 7) << 6) + (col & 63)];
                    float vf = vfi[(size_t)row * 1024 + col];
                    VFIN[(size_t)row * 1024 + col] = vr + (vf - vr) * m;
                } else {
                    GARR[(size_t)row * 1024 + col] = v;
                }
            }
        }
    }
}

// ---------------------------------------------------------------------------
// Fused RMS-norm + RoPE (R & K) + prep (kk -> ABUF, BON). cos/sin inline.
// 256-thread blocks: 4 wave-units per block (shuffles stay intra-wave).
// ---------------------------------------------------------------------------
__global__ __launch_bounds__(256) void normrope_prep(
    float* __restrict__ RRAW, float* __restrict__ KRAW,
    float* __restrict__ ABUF,
    const float* __restrict__ rnw, const float* __restrict__ knw,
    const float* __restrict__ rk,
    float* __restrict__ BON)
{
    int unit = blockIdx.x * 4 + (threadIdx.x >> 6);   // bt*8 + hk
    int hk = unit & 7;
    int bt = unit >> 3;
    int b = bt >> 10, t = bt & 1023;
    int lane = threadIdx.x & 63;
    int fi = lane & 31;
    float invf = powf(1.0e6f, -(float)fi * (1.0f / 32.0f));
    float fr = (float)t * invf;
    float c = cosf(fr), s = sinf(fr);

    // ---- K head: norm + rope + kk ----
    size_t kidx = ((size_t)bt * 8 + hk) * 64 + lane;
    float k = KRAW[kidx];
    float ss = k * k;
    #pragma unroll
    for (int m = 1; m < 64; m <<= 1) ss += __shfl_xor(ss, m, 64);
    float kn = k * rsqrtf(ss * (1.f / 64.f) + 1e-6f) * knw[lane];
    float kp = __shfl_xor(kn, 32, 64);
    float kroped = fmaf(kn, c, ((lane < 32) ? -kp : kp) * s);
    KRAW[kidx] = kroped;

    float ss2 = kroped * kroped;
    #pragma unroll
    for (int m = 1; m < 64; m <<= 1) ss2 += __shfl_xor(ss2, m, 64);
    float kk = kroped / fmaxf(sqrtf(ss2), 1e-12f);
    ABUF[kidx] = -kk;

    // ---- R heads (2 per kv head): norm + rope + BON ----
    #pragma unroll
    for (int rep = 0; rep < 2; ++rep) {
        int h = hk * 2 + rep;
        size_t cidx = (size_t)bt * 1024 + h * 64 + lane;
        float r = RRAW[cidx];
        float ssr = r * r;
        #pragma unroll
        for (int m = 1; m < 64; m <<= 1) ssr += __shfl_xor(ssr, m, 64);
        float rn = r * rsqrtf(ssr * (1.f / 64.f) + 1e-6f) * rnw[lane];
        float rp = __shfl_xor(rn, 32, 64);
        float rroped = fmaf(rn, c, ((lane < 32) ? -rp : rp) * s);
        RRAW[cidx] = rroped;

        float bon = rroped * kroped * rk[h * 64 + lane];
        #pragma unroll
        for (int m = 1; m < 64; m <<= 1) bon += __shfl_xor(bon, m, 64);
        if (lane == 0) BON[((size_t)(b * 16 + h)) * 1024 + t] = bon;
    }
}

// ---------------------------------------------------------------------------
// wkv_pass1 (r10 structure — measured equilibrium, DO NOT TOUCH): per-chunk
// zero-state scan, CL=32, ONE wave per chunk holding BOTH P and Z. Operand
// arrays stream through double-buffered LDS via global_load_lds with counted
// vmcnt (81 LDS reads/step). Epilogue writes P transposed+XOR-swizzled.
// Rejected variants: full-readlane (r8 +90%), bf16-pack (r11 +95%),
// phase-A readlane (r13 +18%).
// ---------------------------------------------------------------------------
__global__ __launch_bounds__(64) void wkv_pass1(
    const float* __restrict__ R, const float* __restrict__ Kv,
    const float* __restrict__ Ab, const float* __restrict__ Bhat,
    const float* __restrict__ Dd, const float* __restrict__ Vv,
    float* __restrict__ Q, float* __restrict__ Y0,
    float* __restrict__ PLT, float* __restrict__ ZL)
{
    int blk = blockIdx.x;           // bh*NC + c
    int c   = blk & (NC - 1);
    int bh  = blk >> 5;
    int h   = bh & 15;
    int b   = bh >> 4;
    int hk  = h >> 1;
    int lane = threadIdx.x;
    int t0 = c * CL;

    size_t cb = ((size_t)(b * 1024 + t0)) * 1024 + h * 64;
    size_t kb = ((size_t)(b * 1024 + t0)) * 512 + hk * 64;
    size_t qb = (((size_t)bh) * 1024 + t0) * 64;

    __shared__ __align__(16) float sA[2][64], sB[2][64], sD[2][64],
                                   sR[2][64], sK[2][64], sV[2][64];

    float SP[64], SZ[64];
    #pragma unroll
    for (int j = 0; j < 64; ++j) { SP[j] = (j == lane) ? 1.f : 0.f; SZ[j] = 0.f; }

    auto stage = [&](int u, int buf) {
        stage64(Ab   + kb + (size_t)u * 512,  &sA[buf][0], lane);
        stage64(Bhat + cb + (size_t)u * 1024, &sB[buf][0], lane);
        stage64(Dd   + cb + (size_t)u * 1024, &sD[buf][0], lane);
        stage64(R    + cb + (size_t)u * 1024, &sR[buf][0], lane);
        stage64(Kv   + kb + (size_t)u * 512,  &sK[buf][0], lane);
        stage64(Vv   + cb + (size_t)u * 1024, &sV[buf][0], lane);
    };
    stage(0, 0);

    for (int u = 0; u < CL; ++u) {
        int un = (u + 1 < CL) ? u + 1 : u;
        stage(un, (u + 1) & 1);
        asm volatile("s_waitcnt vmcnt(6)" ::: "memory");
        int cur = u & 1;
        float v = sV[cur][lane];

        float pa0 = 0.f, pa1 = 0.f, za0 = 0.f, za1 = 0.f;
        #pragma unroll
        for (int jc = 0; jc < 16; ++jc) {
            float4 a4 = *reinterpret_cast<const float4*>(&sA[cur][jc * 4]);
            pa0 = fmaf(SP[jc*4+0], a4.x, pa0); za0 = fmaf(SZ[jc*4+0], a4.x, za0);
            pa1 = fmaf(SP[jc*4+1], a4.y, pa1); za1 = fmaf(SZ[jc*4+1], a4.y, za1);
            pa0 = fmaf(SP[jc*4+2], a4.z, pa0); za0 = fmaf(SZ[jc*4+2], a4.z, za0);
            pa1 = fmaf(SP[jc*4+3], a4.w, pa1); za1 = fmaf(SZ[jc*4+3], a4.w, za1);
        }
        float pa = pa0 + pa1;
        float za = za0 + za1;

        float q0 = 0.f, q1 = 0.f, y0a = 0.f, y1a = 0.f;
        #pragma unroll
        for (int jc = 0; jc < 16; ++jc) {
            float4 d4 = *reinterpret_cast<const float4*>(&sD[cur][jc * 4]);
            float4 b4 = *reinterpret_cast<const float4*>(&sB[cur][jc * 4]);
            float4 k4 = *reinterpret_cast<const float4*>(&sK[cur][jc * 4]);
            float4 r4 = *reinterpret_cast<const float4*>(&sR[cur][jc * 4]);
            SP[jc*4+0] = fmaf(SP[jc*4+0], d4.x, pa * b4.x); q0  = fmaf(SP[jc*4+0], r4.x, q0);
            SZ[jc*4+0] = fmaf(SZ[jc*4+0], d4.x, fmaf(za, b4.x, v * k4.x)); y0a = fmaf(SZ[jc*4+0], r4.x, y0a);
            SP[jc*4+1] = fmaf(SP[jc*4+1], d4.y, pa * b4.y); q1  = fmaf(SP[jc*4+1], r4.y, q1);
            SZ[jc*4+1] = fmaf(SZ[jc*4+1], d4.y, fmaf(za, b4.y, v * k4.y)); y1a = fmaf(SZ[jc*4+1], r4.y, y1a);
            SP[jc*4+2] = fmaf(SP[jc*4+2], d4.z, pa * b4.z); q0  = fmaf(SP[jc*4+2], r4.z, q0);
            SZ[jc*4+2] = fmaf(SZ[jc*4+2], d4.z, fmaf(za, b4.z, v * k4.z)); y0a = fmaf(SZ[jc*4+2], r4.z, y0a);
            SP[jc*4+3] = fmaf(SP[jc*4+3], d4.w, pa * b4.w); q1  = fmaf(SP[jc*4+3], r4.w, q1);
            SZ[jc*4+3] = fmaf(SZ[jc*4+3], d4.w, fmaf(za, b4.w, v * k4.w)); y1a = fmaf(SZ[jc*4+3], r4.w, y1a);
        }
        Q[qb + (size_t)u * 64 + lane]    = q0 + q1;
        Y0[cb + (size_t)u * 1024 + lane] = y0a + y1a;
    }

    // P transposed + swizzled: PLT[col*64 + (row ^ ((col&7)<<2))] = P[row][col]
    size_t pbT = (size_t)blk * 4096;
    #pragma unroll
    for (int j = 0; j < 64; ++j)
        PLT[pbT + j * 64 + (lane ^ ((j & 7) << 2))] = SP[j];
    size_t pb = pbT + (size_t)lane * 64;
    #pragma unroll
    for (int j = 0; j < 64; j += 4)
        *reinterpret_cast<float4*>(&ZL[pb + j]) =
            make_float4(SZ[j], SZ[j + 1], SZ[j + 2], SZ[j + 3]);
}

// ---------------------------------------------------------------------------
// wkv_pass2 (r8 version): chunk-state propagation, row-parallel. 256 blocks =
// (bh, 16-row group); 4 waves x 4 rows, lane = column. S rows in VGPRs;
// row-broadcast via readlane; P staged column-major+swizzled to LDS.
// ---------------------------------------------------------------------------
__global__ __launch_bounds__(256) void wkv_pass2(
    const float* __restrict__ PLT, float* ZLio)
{
    int blk = blockIdx.x;        // bh*4 + rg
    int rg  = blk & 3;
    int bh  = blk >> 2;
    int tid = threadIdx.x, lane = tid & 63, wv = tid >> 6;

    __shared__ __align__(16) float Pld[2][4096];
    __shared__ __align__(16) float Zld[2][1024];

    float S0 = 0.f, S1 = 0.f, S2 = 0.f, S3 = 0.f;

    auto stage = [&](int cc, int buf) {
        size_t pbase = ((size_t)bh * NC + cc) * 4096;
        #pragma unroll
        for (int i = 0; i < 4; ++i) {
            const float* src = PLT + pbase + (size_t)(i * 256 + tid) * 4;
            float* dst = &Pld[buf][(i * 256 + wv * 64) * 4];
            __builtin_amdgcn_global_load_lds(
                (const __attribute__((address_space(1))) uint32_t*)src,
                (__attribute__((address_space(3))) uint32_t*)dst, 16, 0, 0);
        }
        const float* zsrc = ZLio + pbase + (size_t)rg * 1024 + (size_t)tid * 4;
        float* zdst = &Zld[buf][wv * 256];
        __builtin_amdgcn_global_load_lds(
            (const __attribute__((address_space(1))) uint32_t*)zsrc,
            (__attribute__((address_space(3))) uint32_t*)zdst, 16, 0, 0);
    };

    stage(0, 0);

    for (int cc = 0; cc < NC; ++cc) {
        int cur = cc & 1;
        if (cc + 1 < NC) {
            stage(cc + 1, cur ^ 1);
            asm volatile("s_waitcnt vmcnt(5)" ::: "memory");
        } else {
            asm volatile("s_waitcnt vmcnt(0)" ::: "memory");
        }
        __syncthreads();

        size_t sb = ((size_t)bh * NC + cc) * 4096 + (size_t)(rg * 16 + wv * 4) * 64 + lane;
        ZLio[sb]       = S0;
        ZLio[sb + 64]  = S1;
        ZLio[sb + 128] = S2;
        ZLio[sb + 192] = S3;
        if (cc == NC - 1) break;

        int zb = (wv * 4) * 64 + lane;
        float acc0 = Zld[cur][zb],       acc1 = Zld[cur][zb + 64],
              acc2 = Zld[cur][zb + 128], acc3 = Zld[cur][zb + 192];
        const float* pcol = &Pld[cur][lane * 64];
        int swz = (lane & 7) << 2;
        #pragma unroll
        for (int m4 = 0; m4 < 64; m4 += 4) {
            float4 p4 = *reinterpret_cast<const float4*>(&pcol[m4 ^ swz]);
            #pragma unroll
            for (int s = 0; s < 4; ++s) {
                float pv = (&p4.x)[s];
                acc0 = fmaf(rlane(S0, m4 + s), pv, acc0);
                acc1 = fmaf(rlane(S1, m4 + s), pv, acc1);
                acc2 = fmaf(rlane(S2, m4 + s), pv, acc2);
                acc3 = fmaf(rlane(S3, m4 + s), pv, acc3);
            }
        }
        S0 = acc0; S1 = acc1; S2 = acc2; S3 = acc3;
        __syncthreads();
    }
}

// ---------------------------------------------------------------------------
// wkv_pass3 v2: y = (y0 + Sstart.q + bon*v) * g -> bf16. HALF-CHUNK split:
// 2 waves per chunk (16 steps each, sharing the chunk-start state) ->
// 2048 blocks = 2x occupancy for this latency-bound finalize.
// ---------------------------------------------------------------------------
__global__ __launch_bounds__(64) void wkv_pass3(
    const float* __restrict__ SST, const float* __restrict__ Q,
    const float* __restrict__ Vv, const float* __restrict__ G,
    const float* __restrict__ BON, const float* __restrict__ Y0,
    uint16_t* __restrict__ Yb)
{
    int blk = blockIdx.x;   // bh*(2*NC) + c2
    int c2 = blk & (2 * NC - 1), bh = blk >> 6, h = bh & 15, b = bh >> 4;
    int cchunk = c2 >> 1;
    int lane = threadIdx.x;
    int t0 = c2 * (CL / 2);

    __shared__ __align__(16) float qs[2][64];
    __shared__ float bons[CL / 2];
    if (lane < CL / 2) bons[lane] = BON[((size_t)bh) * 1024 + t0 + lane];

    float S[64];
    size_t sb = ((size_t)(bh * NC + cchunk)) * 4096 + (size_t)lane * 64;
    #pragma unroll
    for (int jc = 0; jc < 16; ++jc) {
        float4 s4 = *reinterpret_cast<const float4*>(&SST[sb + jc * 4]);
        S[jc*4+0] = s4.x; S[jc*4+1] = s4.y; S[jc*4+2] = s4.z; S[jc*4+3] = s4.w;
    }

    size_t cb = ((size_t)(b * 1024 + t0)) * 1024 + h * 64 + lane;
    size_t qbase = (((size_t)bh) * 1024 + t0) * 64;

    stage64(Q + qbase, &qs[0][0], lane);
    for (int u = 0; u < CL / 2; ++u) {
        int un = (u + 1 < CL / 2) ? u + 1 : u;
        stage64(Q + qbase + (size_t)un * 64, &qs[(u + 1) & 1][0], lane);
        asm volatile("s_waitcnt vmcnt(1)" ::: "memory");
        int cur = u & 1;

        float d0 = 0.f, d1 = 0.f, d2 = 0.f, d3 = 0.f;
        #pragma unroll
        for (int jc = 0; jc < 16; ++jc) {
            float4 q4 = *reinterpret_cast<const float4*>(&qs[cur][jc * 4]);
            d0 = fmaf(S[jc*4+0], q4.x, d0);
            d1 = fmaf(S[jc*4+1], q4.y, d1);
            d2 = fmaf(S[jc*4+2], q4.z, d2);
            d3 = fmaf(S[jc*4+3], q4.w, d3);
        }
        float dot = (d0 + d1) + (d2 + d3);
        float y0 = Y0[cb + (size_t)u * 1024];
        float vc = Vv[cb + (size_t)u * 1024];
        float gc = G[cb + (size_t)u * 1024];
        float bon = bons[u];
        Yb[cb + (size_t)u * 1024] = f2bf((y0 + dot + bon * vc) * gc);
    }
}

// ---------------------------------------------------------------------------
extern "C" void kernel_launch(void* const* d_in, const int* in_sizes, int n_in,
                              void* d_out, int out_size, void* d_ws, size_t ws_size,
                              hipStream_t stream)
{
    const float* x   = (const float*)d_in[0];
    const float* vfi = (const float*)d_in[1];
    const float* Wr  = (const float*)d_in[2];
    const float* Wk  = (const float*)d_in[3];
    const float* Wv  = (const float*)d_in[4];
    const float* Wo  = (const float*)d_in[5];
    const float* w0  = (const float*)d_in[6];
    const float* w1  = (const float*)d_in[7];
    const float* w2  = (const float*)d_in[8];
    const float* a0  = (const float*)d_in[9];
    const float* a1  = (const float*)d_in[10];
    const float* a2  = (const float*)d_in[11];
    const float* v0  = (const float*)d_in[12];
    const float* v1  = (const float*)d_in[13];
    const float* v2  = (const float*)d_in[14];
    const float* g1  = (const float*)d_in[15];
    const float* g2  = (const float*)d_in[16];
    const float* rk  = (const float*)d_in[17];
    const float* rnw = (const float*)d_in[18];
    const float* knw = (const float*)d_in[19];

    float* ws = (float*)d_ws;
    size_t o = 0;
    float* RRAW = ws + o; o += (size_t)MT * 1024;
    float* KRAW = ws + o; o += (size_t)MT * 512;
    float* VRAW = ws + o; o += (size_t)MT * 512;
    float* DEC  = ws + o; o += (size_t)MT * 1024;
    float* AARR = ws + o; o += (size_t)MT * 1024;
    float* GARR = ws + o; o += (size_t)MT * 1024;
    float* VFIN = ws + o; o += (size_t)MT * 1024;
    float* YARR = ws + o; o += (size_t)MT * 1024;  // y0 from pass1
    float* ABUF = ws + o; o += (size_t)MT * 512;
    float* QBUF = ws + o; o += (size_t)MT * 1024;
    float* PLB  = ws + o; o += (size_t)(Bb * Hh * NC) * 4096;  // 32 MB (transposed+swizzled)
    float* ZLB  = ws + o; o += (size_t)(Bb * Hh * NC) * 4096;  // 32 MB (becomes SST)
    float* BON  = ws + o; o += (size_t)64 * 1024;
    uint16_t* XB   = (uint16_t*)(ws + o); o += (size_t)MT * 512;
    uint16_t* WCAT = (uint16_t*)(ws + o); o += (size_t)NCAT * 512;
    uint16_t* WoT  = (uint16_t*)(ws + o); o += (size_t)1024 * 512;
    uint16_t* W1b  = (uint16_t*)(ws + o); o += (size_t)MT * 32;   // [MT][64] bf16
    uint16_t* A1b  = (uint16_t*)(ws + o); o += (size_t)MT * 32;
    uint16_t* V1b  = (uint16_t*)(ws + o); o += (size_t)MT * 32;   // [MT][64], cols 32+ zero
    uint16_t* G1b  = (uint16_t*)(ws + o); o += (size_t)MT * 96;   // [MT][192], cols 160+ zero
    uint16_t* LW   = (uint16_t*)(ws + o); o += (size_t)1024 * 32; // w2^T [1024][64]
    uint16_t* LA   = (uint16_t*)(ws + o); o += (size_t)1024 * 32;
    uint16_t* LV   = (uint16_t*)(ws + o); o += (size_t)1024 * 32;
    uint16_t* LG   = (uint16_t*)(ws + o); o += (size_t)1024 * 96; // g2^T [1024][192]
    uint16_t* YB = XB;          // alias: XB dead after stage-1 GEMM

    // stage 0: weight transposes + x->bf16 + v_first copy, one launch (z=12 = conv)
    transpose_all_kernel<<<dim3(32, 32, 13), dim3(256), 0, stream>>>(
        Wr, Wk, Wv, w1, a1, v1, g1, Wo, w2, a2, v2, g2, WCAT, WoT, LW, LA, LV, LG,
        x, XB, (const float4*)vfi, (float4*)((float*)d_out + (size_t)MT * 1024));

    dim3 blk(256);

    // stage 1: all projections in one bf16 MFMA GEMM (N = 2432)
    gemm_bf16_proj<<<dim3(NCAT / 128, MT / 128), blk, 0, stream>>>(
        XB, WCAT, MT, NCAT, 1024, RRAW, KRAW, VRAW, W1b, A1b, V1b, G1b);

    // stage 2: fused RMS norm + RoPE + kk/BON prep (before lora2: it feeds ABUF)
    normrope_prep<<<dim3(MT * HKVn / 4), dim3(256), 0, stream>>>(
        RRAW, KRAW, ABUF, rnw, knw, rk, BON);

    // stage 3: all LoRA second matmuls in one fused MFMA launch (interleaved segs)
    lora2_mfma<<<dim3(32, MT / 128), blk, 0, stream>>>(
        W1b, A1b, V1b, G1b, LW, LA, LV, LG, w0, a0, v0, VRAW, vfi, ABUF,
        DEC, AARR, VFIN, GARR);

    // stage 4: chunk-parallel WKV scan
    wkv_pass1<<<dim3(Bb * Hh * NC), dim3(64), 0, stream>>>(
        RRAW, KRAW, ABUF, AARR, DEC, VFIN, QBUF, YARR, PLB, ZLB);
    wkv_pass2<<<dim3(Bb * Hh * 4), dim3(256), 0, stream>>>(PLB, ZLB);
    wkv_pass3<<<dim3(Bb * Hh * NC * 2), dim3(64), 0, stream>>>(
        ZLB, QBUF, VFIN, GARR, BON, YARR, YB);

    // stage 5: out = (y*g) @ Wo (bf16 MFMA)
    gemm_bf16<<<dim3(1024 / 128, MT / 128), blk, 0, stream>>>(
        YB, WoT, (float*)d_out, MT, 1024, 1024);
}